// Round 1
// baseline (3642.722 us; speedup 1.0000x reference)
//
#include <hip/hip_runtime.h>
#include <hip/hip_bf16.h>

#define DD 128
#define RR 8

// ---------------- count edges per (dst, rel) and in-degree ----------------
__global__ __launch_bounds__(256) void count_k(const int* __restrict__ edst,
    const int* __restrict__ etyp, int* __restrict__ cnt, int* __restrict__ deg, int E) {
  int i = blockIdx.x * 256 + threadIdx.x;
  if (i < E) {
    int d = edst[i];
    atomicAdd(&cnt[d * RR + etyp[i]], 1);
    atomicAdd(&deg[d], 1);
  }
}

__global__ __launch_bounds__(256) void invc_k(const int* __restrict__ cnt,
    float* __restrict__ invc, int n) {
  int i = blockIdx.x * 256 + threadIdx.x;
  if (i < n) {
    int c = cnt[i];
    invc[i] = 1.0f / (float)(c < 1 ? 1 : c);
  }
}

// ---------------- scatter h[src] into msg[(dst*R+rel)*D] ----------------
__global__ __launch_bounds__(256) void scatter_k(const float* __restrict__ h,
    const int* __restrict__ esrc, const int* __restrict__ edst,
    const int* __restrict__ etyp, float* __restrict__ msg, int E) {
  int gid = blockIdx.x * 256 + threadIdx.x;
  int e = gid >> 5, q = gid & 31;
  if (e < E) {
    int s = esrc[e], d = edst[e], r = etyp[e];
    float4 v = *(const float4*)(h + (size_t)s * DD + q * 4);
    float* p = msg + ((size_t)d * RR + r) * DD + q * 4;
    atomicAdd(p + 0, v.x);
    atomicAdd(p + 1, v.y);
    atomicAdd(p + 2, v.z);
    atomicAdd(p + 3, v.w);
  }
}

// ---------------- composite RGCN GEMM: out = [h | msg/cnt] @ [Wself; Wrel] ----------------
// M = nN, K = 1152, N = 128. Block: 256 threads, 128 rows x 128 cols, 8x8/thread.
template <bool RELU>
__global__ __launch_bounds__(256) void rgcn_gemm(const float* __restrict__ h,
    const float* __restrict__ msg, const float* __restrict__ invc,
    const float* __restrict__ Wself, const float* __restrict__ Wrel,
    float* __restrict__ out, int nN) {
  __shared__ float As[16][128];  // [k][m] transposed
  __shared__ float Bs[16][128];  // [k][n]
  const int t = threadIdx.x;
  const int row0 = blockIdx.x * 128;
  const int trow = t >> 4, tcol = t & 15;
  float acc[8][8];
#pragma unroll
  for (int i = 0; i < 8; ++i)
#pragma unroll
    for (int j = 0; j < 8; ++j) acc[i][j] = 0.f;

  for (int kc = 0; kc < DD + RR * DD; kc += 16) {
    // A tile: 128 rows x 16 k, one float4 along k per load
#pragma unroll
    for (int i = 0; i < 2; ++i) {
      int q = t * 2 + i;
      int m = q >> 2, kq = (q & 3) * 4;
      int mg = row0 + m;
      if (mg >= nN) mg = nN - 1;
      int k = kc + kq;
      float4 v;
      if (k < DD) {
        v = *(const float4*)(h + (size_t)mg * DD + k);
      } else {
        int rd = k - DD;  // r*128 + d, contiguous in msg
        v = *(const float4*)(msg + (size_t)mg * (RR * DD) + rd);
        float ic = invc[mg * RR + (rd >> 7)];
        v.x *= ic; v.y *= ic; v.z *= ic; v.w *= ic;
      }
      As[kq + 0][m] = v.x;
      As[kq + 1][m] = v.y;
      As[kq + 2][m] = v.z;
      As[kq + 3][m] = v.w;
    }
    // B tile: 16 k x 128 cols
#pragma unroll
    for (int i = 0; i < 2; ++i) {
      int q = t * 2 + i;
      int kk = q >> 5, hc = (q & 31) * 4;
      int k = kc + kk;
      const float* src = (k < DD) ? (Wself + (size_t)k * DD + hc)
                                  : (Wrel + (size_t)(k - DD) * DD + hc);
      *(float4*)&Bs[kk][hc] = *(const float4*)src;
    }
    __syncthreads();
#pragma unroll
    for (int kk = 0; kk < 16; ++kk) {
      float4 a0 = *(float4*)&As[kk][trow * 8];
      float4 a1 = *(float4*)&As[kk][trow * 8 + 4];
      float4 b0 = *(float4*)&Bs[kk][tcol * 8];
      float4 b1 = *(float4*)&Bs[kk][tcol * 8 + 4];
      float a[8] = {a0.x, a0.y, a0.z, a0.w, a1.x, a1.y, a1.z, a1.w};
      float b[8] = {b0.x, b0.y, b0.z, b0.w, b1.x, b1.y, b1.z, b1.w};
#pragma unroll
      for (int i = 0; i < 8; ++i)
#pragma unroll
        for (int j = 0; j < 8; ++j) acc[i][j] += a[i] * b[j];
    }
    __syncthreads();
  }
#pragma unroll
  for (int i = 0; i < 8; ++i) {
    int rg = row0 + trow * 8 + i;
    if (rg < nN) {
      float4 o0 = make_float4(acc[i][0], acc[i][1], acc[i][2], acc[i][3]);
      float4 o1 = make_float4(acc[i][4], acc[i][5], acc[i][6], acc[i][7]);
      if (RELU) {
        o0.x = fmaxf(o0.x, 0.f); o0.y = fmaxf(o0.y, 0.f);
        o0.z = fmaxf(o0.z, 0.f); o0.w = fmaxf(o0.w, 0.f);
        o1.x = fmaxf(o1.x, 0.f); o1.y = fmaxf(o1.y, 0.f);
        o1.z = fmaxf(o1.z, 0.f); o1.w = fmaxf(o1.w, 0.f);
      }
      *(float4*)(out + (size_t)rg * DD + tcol * 8) = o0;
      *(float4*)(out + (size_t)rg * DD + tcol * 8 + 4) = o1;
    }
  }
}

// ---------------- gather disease rows of h2 ----------------
__global__ __launch_bounds__(256) void gather_k(const float* __restrict__ h2,
    const int* __restrict__ bli, float* __restrict__ hbp, int nd) {
  int gid = blockIdx.x * 256 + threadIdx.x;
  int i = gid >> 5, q = gid & 31;
  if (i < nd) {
    *(float4*)(hbp + (size_t)i * DD + q * 4) =
        *(const float4*)(h2 + (size_t)bli[i] * DD + q * 4);
  }
}

// ---------------- row sums of permuted sim matrix ----------------
__global__ __launch_bounds__(256) void rowsum_k(const float* __restrict__ sim,
    const int* __restrict__ mri, float* __restrict__ rs, int nd) {
  __shared__ float red[256];
  int i = blockIdx.x;
  const float* row = sim + (size_t)mri[i] * nd;
  float s = 0.f;
  for (int j = threadIdx.x; j < nd; j += 256) s += row[mri[j]];
  red[threadIdx.x] = s;
  __syncthreads();
  for (int o = 128; o > 0; o >>= 1) {
    if (threadIdx.x < o) red[threadIdx.x] += red[threadIdx.x + o];
    __syncthreads();
  }
  if (threadIdx.x == 0) rs[i] = red[0] + 1e-9f;
}

// ---------------- hs = sim_perm @ hbp (raw, unnormalized) ----------------
__global__ __launch_bounds__(256) void sim_gemm(const float* __restrict__ sim,
    const float* __restrict__ hbp, const int* __restrict__ mri,
    float* __restrict__ hs, int nd) {
  __shared__ float As[16][128];
  __shared__ float Bs[16][128];
  const int t = threadIdx.x;
  const int row0 = blockIdx.x * 128;
  const int trow = t >> 4, tcol = t & 15;
  float acc[8][8];
#pragma unroll
  for (int i = 0; i < 8; ++i)
#pragma unroll
    for (int j = 0; j < 8; ++j) acc[i][j] = 0.f;

  // A-loader mapping: this thread owns row m = t>>1, k-half kb
  const int m = t >> 1, kb = (t & 1) * 8;
  int mg = row0 + m;
  if (mg >= nd) mg = nd - 1;
  const float* simrow = sim + (size_t)mri[mg] * nd;

  for (int kc = 0; kc < nd; kc += 16) {  // nd = 4000, divisible by 16
#pragma unroll
    for (int i = 0; i < 8; ++i) {
      As[kb + i][m] = simrow[mri[kc + kb + i]];
    }
#pragma unroll
    for (int i = 0; i < 2; ++i) {
      int q = t * 2 + i;
      int kk = q >> 5, hc = (q & 31) * 4;
      *(float4*)&Bs[kk][hc] = *(const float4*)(hbp + (size_t)(kc + kk) * DD + hc);
    }
    __syncthreads();
#pragma unroll
    for (int kk = 0; kk < 16; ++kk) {
      float4 a0 = *(float4*)&As[kk][trow * 8];
      float4 a1 = *(float4*)&As[kk][trow * 8 + 4];
      float4 b0 = *(float4*)&Bs[kk][tcol * 8];
      float4 b1 = *(float4*)&Bs[kk][tcol * 8 + 4];
      float a[8] = {a0.x, a0.y, a0.z, a0.w, a1.x, a1.y, a1.z, a1.w};
      float b[8] = {b0.x, b0.y, b0.z, b0.w, b1.x, b1.y, b1.z, b1.w};
#pragma unroll
      for (int i = 0; i < 8; ++i)
#pragma unroll
        for (int j = 0; j < 8; ++j) acc[i][j] += a[i] * b[j];
    }
    __syncthreads();
  }
#pragma unroll
  for (int i = 0; i < 8; ++i) {
    int rg = row0 + trow * 8 + i;
    if (rg < nd) {
      *(float4*)(hs + (size_t)rg * DD + tcol * 8) =
          make_float4(acc[i][0], acc[i][1], acc[i][2], acc[i][3]);
      *(float4*)(hs + (size_t)rg * DD + tcol * 8 + 4) =
          make_float4(acc[i][4], acc[i][5], acc[i][6], acc[i][7]);
    }
  }
}

// ---------------- final blend into d_out at disease rows ----------------
__global__ __launch_bounds__(256) void final_k(const float* __restrict__ hs,
    const float* __restrict__ hbp, const float* __restrict__ rs,
    const int* __restrict__ bli, const int* __restrict__ deg,
    float* __restrict__ out, int nd) {
  int gid = blockIdx.x * 256 + threadIdx.x;
  int i = gid >> 5, q = gid & 31;
  if (i < nd) {
    int g = bli[i];
    float cg = 0.7f * expf(-0.7f * (float)deg[g]) + 0.2f;
    float inv = 1.0f / rs[i];
    float4 s = *(const float4*)(hs + (size_t)i * DD + q * 4);
    float4 b = *(const float4*)(hbp + (size_t)i * DD + q * 4);
    float4 o;
    o.x = cg * (s.x * inv) + (1.f - cg) * b.x;
    o.y = cg * (s.y * inv) + (1.f - cg) * b.y;
    o.z = cg * (s.z * inv) + (1.f - cg) * b.z;
    o.w = cg * (s.w * inv) + (1.f - cg) * b.w;
    *(float4*)(out + (size_t)g * DD + q * 4) = o;
  }
}

extern "C" void kernel_launch(void* const* d_in, const int* in_sizes, int n_in,
                              void* d_out, int out_size, void* d_ws, size_t ws_size,
                              hipStream_t stream) {
  const float* x   = (const float*)d_in[0];
  const float* sim = (const float*)d_in[1];
  const float* W1s = (const float*)d_in[2];
  const float* W1r = (const float*)d_in[3];
  const float* W2s = (const float*)d_in[4];
  const float* W2r = (const float*)d_in[5];
  const int* esrc  = (const int*)d_in[6];
  const int* edst  = (const int*)d_in[7];
  const int* etyp  = (const int*)d_in[8];
  const int* bli   = (const int*)d_in[9];
  const int* mri   = (const int*)d_in[10];
  const int N  = in_sizes[0] / DD;
  const int E  = in_sizes[6];
  const int ND = in_sizes[9];
  float* out = (float*)d_out;

  // workspace carve-up (~191 MB)
  char* w = (char*)d_ws;
  float* msg  = (float*)w; w += (size_t)N * RR * DD * sizeof(float);
  float* h1   = (float*)w; w += (size_t)N * DD * sizeof(float);
  float* hbp  = (float*)w; w += (size_t)ND * DD * sizeof(float);
  float* hs   = (float*)w; w += (size_t)ND * DD * sizeof(float);
  float* invc = (float*)w; w += (size_t)N * RR * sizeof(float);
  int*   cnt  = (int*)w;   w += (size_t)N * RR * sizeof(int);
  int*   deg  = (int*)w;   w += (size_t)N * sizeof(int);
  float* rs   = (float*)w; w += (size_t)ND * sizeof(float);

  // counts (shared by both layers) + in-degree
  hipMemsetAsync(cnt, 0, (size_t)(N * RR + N) * sizeof(int), stream);
  count_k<<<(E + 255) / 256, 256, 0, stream>>>(edst, etyp, cnt, deg, E);
  invc_k<<<(N * RR + 255) / 256, 256, 0, stream>>>(cnt, invc, N * RR);

  // layer 1
  hipMemsetAsync(msg, 0, (size_t)N * RR * DD * sizeof(float), stream);
  scatter_k<<<(E * 32 + 255) / 256, 256, 0, stream>>>(x, esrc, edst, etyp, msg, E);
  rgcn_gemm<true><<<(N + 127) / 128, 256, 0, stream>>>(x, msg, invc, W1s, W1r, h1, N);

  // layer 2 (writes all rows of d_out)
  hipMemsetAsync(msg, 0, (size_t)N * RR * DD * sizeof(float), stream);
  scatter_k<<<(E * 32 + 255) / 256, 256, 0, stream>>>(h1, esrc, edst, etyp, msg, E);
  rgcn_gemm<false><<<(N + 127) / 128, 256, 0, stream>>>(h1, msg, invc, W2s, W2r, out, N);

  // similarity diffusion on disease rows
  gather_k<<<(ND * 32 + 255) / 256, 256, 0, stream>>>(out, bli, hbp, ND);
  rowsum_k<<<ND, 256, 0, stream>>>(sim, mri, rs, ND);
  sim_gemm<<<(ND + 127) / 128, 256, 0, stream>>>(sim, hbp, mri, hs, ND);
  final_k<<<(ND * 32 + 255) / 256, 256, 0, stream>>>(hs, hbp, rs, bli, deg, out, ND);
}

// Round 2
// 1113.503 us; speedup vs baseline: 3.2714x; 3.2714x over previous
//
#include <hip/hip_runtime.h>
#include <hip/hip_bf16.h>

#define DD 128
#define RR 8
#define SCAN_CHUNK 2048
#define KSPLIT 10

// ---------------- count edges per (dst, rel) and in-degree ----------------
__global__ __launch_bounds__(256) void count_k(const int* __restrict__ edst,
    const int* __restrict__ etyp, int* __restrict__ cnt, int* __restrict__ deg, int E) {
  int i = blockIdx.x * 256 + threadIdx.x;
  if (i < E) {
    int d = edst[i];
    atomicAdd(&cnt[d * RR + etyp[i]], 1);
    atomicAdd(&deg[d], 1);
  }
}

// ---------------- 3-phase exclusive scan of cnt -> off ----------------
__global__ __launch_bounds__(256) void scan_a(const int* __restrict__ cnt,
    int* __restrict__ off, int* __restrict__ bsum, int n) {
  __shared__ int red[256];
  int base = blockIdx.x * SCAN_CHUNK + threadIdx.x * 8;
  int v[8];
  int s = 0;
#pragma unroll
  for (int i = 0; i < 8; ++i) {
    int idx = base + i;
    v[i] = s;  // exclusive within this thread's run
    s += (idx < n) ? cnt[idx] : 0;
  }
  red[threadIdx.x] = s;
  __syncthreads();
  for (int o = 1; o < 256; o <<= 1) {
    int t = (threadIdx.x >= o) ? red[threadIdx.x - o] : 0;
    __syncthreads();
    red[threadIdx.x] += t;
    __syncthreads();
  }
  int pre = (threadIdx.x > 0) ? red[threadIdx.x - 1] : 0;
#pragma unroll
  for (int i = 0; i < 8; ++i) {
    int idx = base + i;
    if (idx < n) off[idx] = v[i] + pre;
  }
  if (threadIdx.x == 255) bsum[blockIdx.x] = red[255];
}

__global__ void scan_b(int* __restrict__ bsum, int nb) {
  if (threadIdx.x == 0) {
    int s = 0;
    for (int i = 0; i < nb; ++i) { int t = bsum[i]; bsum[i] = s; s += t; }
  }
}

__global__ __launch_bounds__(256) void scan_c(int* __restrict__ off,
    const int* __restrict__ bsum, int n) {
  int i = blockIdx.x * 256 + threadIdx.x;
  if (i < n) off[i] += bsum[i >> 11];  // SCAN_CHUNK = 2048
}

// ---------------- fill CSR: eidx[pos] = src, sorted by (dst,rel) segment ----------------
__global__ __launch_bounds__(256) void fill_k(const int* __restrict__ esrc,
    const int* __restrict__ edst, const int* __restrict__ etyp,
    int* __restrict__ cur, int* __restrict__ eidx, int E) {
  int e = blockIdx.x * 256 + threadIdx.x;
  if (e < E) {
    int seg = edst[e] * RR + etyp[e];
    int p = atomicAdd(&cur[seg], 1);
    eidx[p] = esrc[e];
  }
}

// ---------------- gather-aggregate: msg[seg] = mean of h[src] over segment ----------------
__global__ __launch_bounds__(256) void agg_k(const float* __restrict__ h,
    const int* __restrict__ off, const int* __restrict__ eidx,
    float* __restrict__ msg, int nseg, int E) {
  int gid = blockIdx.x * 256 + threadIdx.x;
  int seg = gid >> 5, q = gid & 31;
  if (seg >= nseg) return;
  int b = off[seg];
  int e = (seg + 1 < nseg) ? off[seg + 1] : E;
  float4 acc = make_float4(0.f, 0.f, 0.f, 0.f);
  for (int i = b; i < e; ++i) {
    const float4 v = *(const float4*)(h + (size_t)eidx[i] * DD + q * 4);
    acc.x += v.x; acc.y += v.y; acc.z += v.z; acc.w += v.w;
  }
  float ic = (e > b) ? 1.0f / (float)(e - b) : 0.0f;
  acc.x *= ic; acc.y *= ic; acc.z *= ic; acc.w *= ic;
  *(float4*)(msg + (size_t)seg * DD + q * 4) = acc;
}

// ---------------- composite RGCN GEMM: out = [h | msg] @ [Wself; Wrel] ----------------
// M = nN, K = 1152, N = 128. Block: 256 threads, 128x128 tile, 8x8/thread.
template <bool RELU>
__global__ __launch_bounds__(256) void rgcn_gemm(const float* __restrict__ h,
    const float* __restrict__ msg, const float* __restrict__ Wself,
    const float* __restrict__ Wrel, float* __restrict__ out, int nN) {
  __shared__ float As[16][128];  // [k][m]
  __shared__ float Bs[16][128];  // [k][n]
  const int t = threadIdx.x;
  const int row0 = blockIdx.x * 128;
  const int trow = t >> 4, tcol = t & 15;
  float acc[8][8];
#pragma unroll
  for (int i = 0; i < 8; ++i)
#pragma unroll
    for (int j = 0; j < 8; ++j) acc[i][j] = 0.f;

  for (int kc = 0; kc < DD + RR * DD; kc += 16) {
#pragma unroll
    for (int i = 0; i < 2; ++i) {
      int q = t * 2 + i;
      int m = q >> 2, kq = (q & 3) * 4;
      int mg = row0 + m;
      if (mg >= nN) mg = nN - 1;
      int k = kc + kq;
      float4 v;
      if (k < DD) {
        v = *(const float4*)(h + (size_t)mg * DD + k);
      } else {
        v = *(const float4*)(msg + (size_t)mg * (RR * DD) + (k - DD));
      }
      As[kq + 0][m] = v.x;
      As[kq + 1][m] = v.y;
      As[kq + 2][m] = v.z;
      As[kq + 3][m] = v.w;
    }
#pragma unroll
    for (int i = 0; i < 2; ++i) {
      int q = t * 2 + i;
      int kk = q >> 5, hc = (q & 31) * 4;
      int k = kc + kk;
      const float* src = (k < DD) ? (Wself + (size_t)k * DD + hc)
                                  : (Wrel + (size_t)(k - DD) * DD + hc);
      *(float4*)&Bs[kk][hc] = *(const float4*)src;
    }
    __syncthreads();
#pragma unroll
    for (int kk = 0; kk < 16; ++kk) {
      float4 a0 = *(float4*)&As[kk][trow * 8];
      float4 a1 = *(float4*)&As[kk][trow * 8 + 4];
      float4 b0 = *(float4*)&Bs[kk][tcol * 8];
      float4 b1 = *(float4*)&Bs[kk][tcol * 8 + 4];
      float a[8] = {a0.x, a0.y, a0.z, a0.w, a1.x, a1.y, a1.z, a1.w};
      float b[8] = {b0.x, b0.y, b0.z, b0.w, b1.x, b1.y, b1.z, b1.w};
#pragma unroll
      for (int i = 0; i < 8; ++i)
#pragma unroll
        for (int j = 0; j < 8; ++j) acc[i][j] += a[i] * b[j];
    }
    __syncthreads();
  }
#pragma unroll
  for (int i = 0; i < 8; ++i) {
    int rg = row0 + trow * 8 + i;
    if (rg < nN) {
      float4 o0 = make_float4(acc[i][0], acc[i][1], acc[i][2], acc[i][3]);
      float4 o1 = make_float4(acc[i][4], acc[i][5], acc[i][6], acc[i][7]);
      if (RELU) {
        o0.x = fmaxf(o0.x, 0.f); o0.y = fmaxf(o0.y, 0.f);
        o0.z = fmaxf(o0.z, 0.f); o0.w = fmaxf(o0.w, 0.f);
        o1.x = fmaxf(o1.x, 0.f); o1.y = fmaxf(o1.y, 0.f);
        o1.z = fmaxf(o1.z, 0.f); o1.w = fmaxf(o1.w, 0.f);
      }
      *(float4*)(out + (size_t)rg * DD + tcol * 8) = o0;
      *(float4*)(out + (size_t)rg * DD + tcol * 8 + 4) = o1;
    }
  }
}

// ---------------- gather disease rows of h2 ----------------
__global__ __launch_bounds__(256) void gather_k(const float* __restrict__ h2,
    const int* __restrict__ bli, float* __restrict__ hbp, int nd) {
  int gid = blockIdx.x * 256 + threadIdx.x;
  int i = gid >> 5, q = gid & 31;
  if (i < nd) {
    *(float4*)(hbp + (size_t)i * DD + q * 4) =
        *(const float4*)(h2 + (size_t)bli[i] * DD + q * 4);
  }
}

// ---------------- row sums of permuted sim matrix ----------------
__global__ __launch_bounds__(256) void rowsum_k(const float* __restrict__ sim,
    const int* __restrict__ mri, float* __restrict__ rs, int nd) {
  __shared__ float red[256];
  int i = blockIdx.x;
  const float* row = sim + (size_t)mri[i] * nd;
  float s = 0.f;
  for (int j = threadIdx.x; j < nd; j += 256) s += row[mri[j]];
  red[threadIdx.x] = s;
  __syncthreads();
  for (int o = 128; o > 0; o >>= 1) {
    if (threadIdx.x < o) red[threadIdx.x] += red[threadIdx.x + o];
    __syncthreads();
  }
  if (threadIdx.x == 0) rs[i] = red[0] + 1e-9f;
}

// ---------------- hs_part[ks] = partial sim_perm @ hbp over K chunk ----------------
__global__ __launch_bounds__(256) void sim_gemm_split(const float* __restrict__ sim,
    const float* __restrict__ hbp, const int* __restrict__ mri,
    float* __restrict__ hs_part, int nd, int chunk) {
  __shared__ float As[16][128];
  __shared__ float Bs[16][128];
  const int t = threadIdx.x;
  const int row0 = blockIdx.x * 128;
  const int kstart = blockIdx.y * chunk;
  const int kend = min(kstart + chunk, nd);
  const int trow = t >> 4, tcol = t & 15;
  float acc[8][8];
#pragma unroll
  for (int i = 0; i < 8; ++i)
#pragma unroll
    for (int j = 0; j < 8; ++j) acc[i][j] = 0.f;

  const int m = t >> 1, kb = (t & 1) * 8;
  int mg = row0 + m;
  if (mg >= nd) mg = nd - 1;
  const float* simrow = sim + (size_t)mri[mg] * nd;

  for (int kc = kstart; kc < kend; kc += 16) {
#pragma unroll
    for (int i = 0; i < 8; ++i) {
      int k = kc + kb + i;
      As[kb + i][m] = (k < kend) ? simrow[mri[k]] : 0.f;
    }
#pragma unroll
    for (int i = 0; i < 2; ++i) {
      int q = t * 2 + i;
      int kk = q >> 5, hc = (q & 31) * 4;
      int k = kc + kk;
      float4 bv = (k < kend) ? *(const float4*)(hbp + (size_t)k * DD + hc)
                             : make_float4(0.f, 0.f, 0.f, 0.f);
      *(float4*)&Bs[kk][hc] = bv;
    }
    __syncthreads();
#pragma unroll
    for (int kk = 0; kk < 16; ++kk) {
      float4 a0 = *(float4*)&As[kk][trow * 8];
      float4 a1 = *(float4*)&As[kk][trow * 8 + 4];
      float4 b0 = *(float4*)&Bs[kk][tcol * 8];
      float4 b1 = *(float4*)&Bs[kk][tcol * 8 + 4];
      float a[8] = {a0.x, a0.y, a0.z, a0.w, a1.x, a1.y, a1.z, a1.w};
      float b[8] = {b0.x, b0.y, b0.z, b0.w, b1.x, b1.y, b1.z, b1.w};
#pragma unroll
      for (int i = 0; i < 8; ++i)
#pragma unroll
        for (int j = 0; j < 8; ++j) acc[i][j] += a[i] * b[j];
    }
    __syncthreads();
  }
  float* dst = hs_part + (size_t)blockIdx.y * nd * DD;
#pragma unroll
  for (int i = 0; i < 8; ++i) {
    int rg = row0 + trow * 8 + i;
    if (rg < nd) {
      *(float4*)(dst + (size_t)rg * DD + tcol * 8) =
          make_float4(acc[i][0], acc[i][1], acc[i][2], acc[i][3]);
      *(float4*)(dst + (size_t)rg * DD + tcol * 8 + 4) =
          make_float4(acc[i][4], acc[i][5], acc[i][6], acc[i][7]);
    }
  }
}

__global__ __launch_bounds__(256) void reduce_k(const float* __restrict__ part,
    float* __restrict__ hs, int n) {  // n = nd*DD/4 float4s
  int i = blockIdx.x * 256 + threadIdx.x;
  if (i < n) {
    float4 s = make_float4(0.f, 0.f, 0.f, 0.f);
#pragma unroll
    for (int p = 0; p < KSPLIT; ++p) {
      float4 v = *(const float4*)(part + (size_t)p * n * 4 + i * 4);
      s.x += v.x; s.y += v.y; s.z += v.z; s.w += v.w;
    }
    *(float4*)(hs + (size_t)i * 4) = s;
  }
}

// ---------------- final blend into d_out at disease rows ----------------
__global__ __launch_bounds__(256) void final_k(const float* __restrict__ hs,
    const float* __restrict__ hbp, const float* __restrict__ rs,
    const int* __restrict__ bli, const int* __restrict__ deg,
    float* __restrict__ out, int nd) {
  int gid = blockIdx.x * 256 + threadIdx.x;
  int i = gid >> 5, q = gid & 31;
  if (i < nd) {
    int g = bli[i];
    float cg = 0.7f * expf(-0.7f * (float)deg[g]) + 0.2f;
    float inv = 1.0f / rs[i];
    float4 s = *(const float4*)(hs + (size_t)i * DD + q * 4);
    float4 b = *(const float4*)(hbp + (size_t)i * DD + q * 4);
    float4 o;
    o.x = cg * (s.x * inv) + (1.f - cg) * b.x;
    o.y = cg * (s.y * inv) + (1.f - cg) * b.y;
    o.z = cg * (s.z * inv) + (1.f - cg) * b.z;
    o.w = cg * (s.w * inv) + (1.f - cg) * b.w;
    *(float4*)(out + (size_t)g * DD + q * 4) = o;
  }
}

extern "C" void kernel_launch(void* const* d_in, const int* in_sizes, int n_in,
                              void* d_out, int out_size, void* d_ws, size_t ws_size,
                              hipStream_t stream) {
  const float* x   = (const float*)d_in[0];
  const float* sim = (const float*)d_in[1];
  const float* W1s = (const float*)d_in[2];
  const float* W1r = (const float*)d_in[3];
  const float* W2s = (const float*)d_in[4];
  const float* W2r = (const float*)d_in[5];
  const int* esrc  = (const int*)d_in[6];
  const int* edst  = (const int*)d_in[7];
  const int* etyp  = (const int*)d_in[8];
  const int* bli   = (const int*)d_in[9];
  const int* mri   = (const int*)d_in[10];
  const int N  = in_sizes[0] / DD;
  const int E  = in_sizes[6];
  const int ND = in_sizes[9];
  const int NR = N * RR;
  float* out = (float*)d_out;

  // workspace carve-up
  char* w = (char*)d_ws;
  float* msg  = (float*)w; w += (size_t)NR * DD * sizeof(float);   // 163.8 MB
  float* h1   = (float*)w; w += (size_t)N * DD * sizeof(float);    // 20.5 MB
  float* hbp  = (float*)w; w += (size_t)ND * DD * sizeof(float);
  float* hs   = (float*)w; w += (size_t)ND * DD * sizeof(float);
  int*   cnt  = (int*)w;   w += (size_t)NR * sizeof(int);
  int*   deg  = (int*)w;   w += (size_t)N * sizeof(int);
  int*   off  = (int*)w;   w += (size_t)NR * sizeof(int);
  int*   cur  = (int*)w;   w += (size_t)NR * sizeof(int);
  int*   eidx = (int*)w;   w += (size_t)E * sizeof(int);
  int*   bsum = (int*)w;   w += 1024 * sizeof(int);
  float* rs   = (float*)w; w += (size_t)ND * sizeof(float);
  float* hs_part = msg;  // alias: msg is dead by the time sim_gemm runs (20.5MB < 163MB)

  // ---- CSR build (shared by both layers) ----
  hipMemsetAsync(cnt, 0, (size_t)(NR + N) * sizeof(int), stream);
  count_k<<<(E + 255) / 256, 256, 0, stream>>>(edst, etyp, cnt, deg, E);
  int nblk = (NR + SCAN_CHUNK - 1) / SCAN_CHUNK;
  scan_a<<<nblk, 256, 0, stream>>>(cnt, off, bsum, NR);
  scan_b<<<1, 256, 0, stream>>>(bsum, nblk);
  scan_c<<<(NR + 255) / 256, 256, 0, stream>>>(off, bsum, NR);
  hipMemcpyAsync(cur, off, (size_t)NR * sizeof(int), hipMemcpyDeviceToDevice, stream);
  fill_k<<<(E + 255) / 256, 256, 0, stream>>>(esrc, edst, etyp, cur, eidx, E);

  // ---- layer 1 ----
  agg_k<<<(NR * 32 + 255) / 256, 256, 0, stream>>>(x, off, eidx, msg, NR, E);
  rgcn_gemm<true><<<(N + 127) / 128, 256, 0, stream>>>(x, msg, W1s, W1r, h1, N);

  // ---- layer 2 (writes all rows of d_out) ----
  agg_k<<<(NR * 32 + 255) / 256, 256, 0, stream>>>(h1, off, eidx, msg, NR, E);
  rgcn_gemm<false><<<(N + 127) / 128, 256, 0, stream>>>(h1, msg, W2s, W2r, out, N);

  // ---- similarity diffusion on disease rows ----
  gather_k<<<(ND * 32 + 255) / 256, 256, 0, stream>>>(out, bli, hbp, ND);
  rowsum_k<<<ND, 256, 0, stream>>>(sim, mri, rs, ND);
  int chunk = (((ND + KSPLIT - 1) / KSPLIT) + 15) & ~15;
  dim3 sgrid((ND + 127) / 128, KSPLIT);
  sim_gemm_split<<<sgrid, 256, 0, stream>>>(sim, hbp, mri, hs_part, ND, chunk);
  reduce_k<<<(ND * DD / 4 + 255) / 256, 256, 0, stream>>>(hs_part, hs, ND * DD / 4);
  final_k<<<(ND * 32 + 255) / 256, 256, 0, stream>>>(hs, hbp, rs, bli, deg, out, ND);
}

// Round 3
// 562.832 us; speedup vs baseline: 6.4721x; 1.9784x over previous
//
#include <hip/hip_runtime.h>
#include <hip/hip_bf16.h>

#define DD 128
#define RR 8
#define KK (DD + RR * DD)  // 1152
#define BK 64
#define SCAN_CHUNK 2048
#define KSPLIT 10

typedef _Float16 h8 __attribute__((ext_vector_type(8)));
typedef _Float16 h4 __attribute__((ext_vector_type(4)));
typedef float f4 __attribute__((ext_vector_type(4)));

// ---------------- count edges per (dst, rel) and in-degree ----------------
__global__ __launch_bounds__(256) void count_k(const int* __restrict__ edst,
    const int* __restrict__ etyp, int* __restrict__ cnt, int* __restrict__ deg, int E) {
  int i = blockIdx.x * 256 + threadIdx.x;
  if (i < E) {
    int d = edst[i];
    atomicAdd(&cnt[d * RR + etyp[i]], 1);
    atomicAdd(&deg[d], 1);
  }
}

// ---------------- 3-phase exclusive scan of cnt -> off ----------------
__global__ __launch_bounds__(256) void scan_a(const int* __restrict__ cnt,
    int* __restrict__ off, int* __restrict__ bsum, int n) {
  __shared__ int red[256];
  int base = blockIdx.x * SCAN_CHUNK + threadIdx.x * 8;
  int v[8];
  int s = 0;
#pragma unroll
  for (int i = 0; i < 8; ++i) {
    int idx = base + i;
    v[i] = s;
    s += (idx < n) ? cnt[idx] : 0;
  }
  red[threadIdx.x] = s;
  __syncthreads();
  for (int o = 1; o < 256; o <<= 1) {
    int t = (threadIdx.x >= o) ? red[threadIdx.x - o] : 0;
    __syncthreads();
    red[threadIdx.x] += t;
    __syncthreads();
  }
  int pre = (threadIdx.x > 0) ? red[threadIdx.x - 1] : 0;
#pragma unroll
  for (int i = 0; i < 8; ++i) {
    int idx = base + i;
    if (idx < n) off[idx] = v[i] + pre;
  }
  if (threadIdx.x == 255) bsum[blockIdx.x] = red[255];
}

__global__ void scan_b(int* __restrict__ bsum, int nb) {
  if (threadIdx.x == 0) {
    int s = 0;
    for (int i = 0; i < nb; ++i) { int t = bsum[i]; bsum[i] = s; s += t; }
  }
}

__global__ __launch_bounds__(256) void scan_c(int* __restrict__ off,
    const int* __restrict__ bsum, int n) {
  int i = blockIdx.x * 256 + threadIdx.x;
  if (i < n) off[i] += bsum[i >> 11];
}

// ---------------- fill CSR ----------------
__global__ __launch_bounds__(256) void fill_k(const int* __restrict__ esrc,
    const int* __restrict__ edst, const int* __restrict__ etyp,
    int* __restrict__ cur, int* __restrict__ eidx, int E) {
  int e = blockIdx.x * 256 + threadIdx.x;
  if (e < E) {
    int seg = edst[e] * RR + etyp[e];
    int p = atomicAdd(&cur[seg], 1);
    eidx[p] = esrc[e];
  }
}

// ---------------- fp32 -> f16 convert of x ----------------
__global__ __launch_bounds__(256) void convx_k(const float* __restrict__ x,
    _Float16* __restrict__ xh, int n4) {
  int i = blockIdx.x * 256 + threadIdx.x;
  if (i < n4) {
    float4 v = *(const float4*)(x + (size_t)i * 4);
    h4 o = {(_Float16)v.x, (_Float16)v.y, (_Float16)v.z, (_Float16)v.w};
    *(h4*)(xh + (size_t)i * 4) = o;
  }
}

// ---------------- build transposed f16 weights WT[n][k], k in [0,1152) ----------------
__global__ __launch_bounds__(256) void convw_k(const float* __restrict__ Ws,
    const float* __restrict__ Wr, _Float16* __restrict__ WT) {
  int gid = blockIdx.x * 256 + threadIdx.x;
  if (gid < DD * KK) {
    int n = gid / KK, k = gid % KK;
    float v = (k < DD) ? Ws[(size_t)k * DD + n] : Wr[(size_t)(k - DD) * DD + n];
    WT[gid] = (_Float16)v;
  }
}

// ---------------- gather-aggregate (f16 in/out, fp32 accumulate) ----------------
__global__ __launch_bounds__(256) void agg_k(const _Float16* __restrict__ h,
    const int* __restrict__ off, const int* __restrict__ eidx,
    _Float16* __restrict__ msg, int nseg, int E) {
  int gid = blockIdx.x * 256 + threadIdx.x;
  int seg = gid >> 5, q = gid & 31;
  if (seg >= nseg) return;
  int b = off[seg];
  int e = (seg + 1 < nseg) ? off[seg + 1] : E;
  float a0 = 0.f, a1 = 0.f, a2 = 0.f, a3 = 0.f;
  for (int i = b; i < e; ++i) {
    h4 v = *(const h4*)(h + (size_t)eidx[i] * DD + q * 4);
    a0 += (float)v[0]; a1 += (float)v[1]; a2 += (float)v[2]; a3 += (float)v[3];
  }
  float ic = (e > b) ? 1.0f / (float)(e - b) : 0.0f;
  h4 o = {(_Float16)(a0 * ic), (_Float16)(a1 * ic),
          (_Float16)(a2 * ic), (_Float16)(a3 * ic)};
  *(h4*)(msg + (size_t)seg * DD + q * 4) = o;
}

// ---------------- MFMA RGCN GEMM: out = [xh | msg] @ WT^T ----------------
// M=nN, K=1152, N=128. 128x128 tile, BK=64, 4 waves of 64x64.
// LDS: As/Bs [128 rows][64 f16] with 16B-chunk XOR swizzle (chunk ^= row&7).
template <bool RELU, bool F16OUT>
__global__ __launch_bounds__(256) void rgcn_mfma(const _Float16* __restrict__ xh,
    const _Float16* __restrict__ msg, const _Float16* __restrict__ WT,
    void* __restrict__ outv, int nN) {
  __shared__ char As[16384];
  __shared__ char Bs[16384];
  const int t = threadIdx.x;
  const int row0 = blockIdx.x * 128;
  const int w = t >> 6, lane = t & 63;
  const int wm = w >> 1, wn = w & 1;
  const int lr = lane & 15, lg = lane >> 4;

  f4 acc[4][4];
#pragma unroll
  for (int mi = 0; mi < 4; ++mi)
#pragma unroll
    for (int ni = 0; ni < 4; ++ni) acc[mi][ni] = (f4){0.f, 0.f, 0.f, 0.f};

  // staging geometry: thread handles 4 chunks (rows r0s+32i, 16B chunk sc)
  const int sc = t & 7;
  const int r0s = t >> 3;
  size_t mg[4];
  int ldsoff[4];
#pragma unroll
  for (int i = 0; i < 4; ++i) {
    int row = r0s + 32 * i;
    ldsoff[i] = row * 128 + ((sc ^ (row & 7)) << 4);
    int m = row0 + row;
    if (m >= nN) m = nN - 1;
    mg[i] = (size_t)m;
  }

  uint4 ra[4], rb[4];
  const int nsteps = KK / BK;

  // prologue: load tile 0
  {
    int kb = sc * 8;
#pragma unroll
    for (int i = 0; i < 4; ++i) {
      const _Float16* p = (kb < DD) ? (xh + mg[i] * DD + kb)
                                    : (msg + mg[i] * (RR * DD) + (kb - DD));
      ra[i] = *(const uint4*)p;
      rb[i] = *(const uint4*)(WT + (size_t)(r0s + 32 * i) * KK + kb);
    }
  }

  for (int ts = 0; ts < nsteps; ++ts) {
#pragma unroll
    for (int i = 0; i < 4; ++i) {
      *(uint4*)(As + ldsoff[i]) = ra[i];
      *(uint4*)(Bs + ldsoff[i]) = rb[i];
    }
    __syncthreads();
    if (ts + 1 < nsteps) {
      int kb = (ts + 1) * BK + sc * 8;
#pragma unroll
      for (int i = 0; i < 4; ++i) {
        const _Float16* p = (kb < DD) ? (xh + mg[i] * DD + kb)
                                      : (msg + mg[i] * (RR * DD) + (kb - DD));
        ra[i] = *(const uint4*)p;
        rb[i] = *(const uint4*)(WT + (size_t)(r0s + 32 * i) * KK + kb);
      }
    }
#pragma unroll
    for (int s = 0; s < 2; ++s) {
      h8 af[4], bf[4];
#pragma unroll
      for (int mi = 0; mi < 4; ++mi) {
        int r = wm * 64 + mi * 16 + lr;
        af[mi] = *(const h8*)(As + r * 128 + (((s * 4 + lg) ^ (r & 7)) << 4));
      }
#pragma unroll
      for (int ni = 0; ni < 4; ++ni) {
        int n = wn * 64 + ni * 16 + lr;
        bf[ni] = *(const h8*)(Bs + n * 128 + (((s * 4 + lg) ^ (n & 7)) << 4));
      }
#pragma unroll
      for (int mi = 0; mi < 4; ++mi)
#pragma unroll
        for (int ni = 0; ni < 4; ++ni)
          acc[mi][ni] = __builtin_amdgcn_mfma_f32_16x16x32_f16(
              af[mi], bf[ni], acc[mi][ni], 0, 0, 0);
    }
    __syncthreads();
  }

  // epilogue: C/D layout col=lane&15, row=(lane>>4)*4+reg
#pragma unroll
  for (int mi = 0; mi < 4; ++mi) {
#pragma unroll
    for (int j = 0; j < 4; ++j) {
      int row = row0 + wm * 64 + mi * 16 + lg * 4 + j;
      if (row < nN) {
#pragma unroll
        for (int ni = 0; ni < 4; ++ni) {
          int col = wn * 64 + ni * 16 + lr;
          float v = acc[mi][ni][j];
          if (RELU) v = fmaxf(v, 0.f);
          if (F16OUT)
            ((_Float16*)outv)[(size_t)row * DD + col] = (_Float16)v;
          else
            ((float*)outv)[(size_t)row * DD + col] = v;
        }
      }
    }
  }
}

// ---------------- gather disease rows of out (fp32) ----------------
__global__ __launch_bounds__(256) void gather_k(const float* __restrict__ h2,
    const int* __restrict__ bli, float* __restrict__ hbp, int nd) {
  int gid = blockIdx.x * 256 + threadIdx.x;
  int i = gid >> 5, q = gid & 31;
  if (i < nd) {
    *(float4*)(hbp + (size_t)i * DD + q * 4) =
        *(const float4*)(h2 + (size_t)bli[i] * DD + q * 4);
  }
}

// ---------------- row sums of permuted sim matrix ----------------
__global__ __launch_bounds__(256) void rowsum_k(const float* __restrict__ sim,
    const int* __restrict__ mri, float* __restrict__ rs, int nd) {
  __shared__ float red[256];
  int i = blockIdx.x;
  const float* row = sim + (size_t)mri[i] * nd;
  float s = 0.f;
  for (int j = threadIdx.x; j < nd; j += 256) s += row[mri[j]];
  red[threadIdx.x] = s;
  __syncthreads();
  for (int o = 128; o > 0; o >>= 1) {
    if (threadIdx.x < o) red[threadIdx.x] += red[threadIdx.x + o];
    __syncthreads();
  }
  if (threadIdx.x == 0) rs[i] = red[0] + 1e-9f;
}

// ---------------- partial sim_perm @ hbp over K chunk ----------------
__global__ __launch_bounds__(256) void sim_gemm_split(const float* __restrict__ sim,
    const float* __restrict__ hbp, const int* __restrict__ mri,
    float* __restrict__ hs_part, int nd, int chunk) {
  __shared__ float As[16][128];
  __shared__ float Bs[16][128];
  const int t = threadIdx.x;
  const int row0 = blockIdx.x * 128;
  const int kstart = blockIdx.y * chunk;
  const int kend = min(kstart + chunk, nd);
  const int trow = t >> 4, tcol = t & 15;
  float acc[8][8];
#pragma unroll
  for (int i = 0; i < 8; ++i)
#pragma unroll
    for (int j = 0; j < 8; ++j) acc[i][j] = 0.f;

  const int m = t >> 1, kb = (t & 1) * 8;
  int mg = row0 + m;
  if (mg >= nd) mg = nd - 1;
  const float* simrow = sim + (size_t)mri[mg] * nd;

  for (int kc = kstart; kc < kend; kc += 16) {
#pragma unroll
    for (int i = 0; i < 8; ++i) {
      int k = kc + kb + i;
      As[kb + i][m] = (k < kend) ? simrow[mri[k]] : 0.f;
    }
#pragma unroll
    for (int i = 0; i < 2; ++i) {
      int q = t * 2 + i;
      int kk = q >> 5, hc = (q & 31) * 4;
      int k = kc + kk;
      float4 bv = (k < kend) ? *(const float4*)(hbp + (size_t)k * DD + hc)
                             : make_float4(0.f, 0.f, 0.f, 0.f);
      *(float4*)&Bs[kk][hc] = bv;
    }
    __syncthreads();
#pragma unroll
    for (int kk = 0; kk < 16; ++kk) {
      float4 a0 = *(float4*)&As[kk][trow * 8];
      float4 a1 = *(float4*)&As[kk][trow * 8 + 4];
      float4 b0 = *(float4*)&Bs[kk][tcol * 8];
      float4 b1 = *(float4*)&Bs[kk][tcol * 8 + 4];
      float a[8] = {a0.x, a0.y, a0.z, a0.w, a1.x, a1.y, a1.z, a1.w};
      float b[8] = {b0.x, b0.y, b0.z, b0.w, b1.x, b1.y, b1.z, b1.w};
#pragma unroll
      for (int i = 0; i < 8; ++i)
#pragma unroll
        for (int j = 0; j < 8; ++j) acc[i][j] += a[i] * b[j];
    }
    __syncthreads();
  }
  float* dst = hs_part + (size_t)blockIdx.y * nd * DD;
#pragma unroll
  for (int i = 0; i < 8; ++i) {
    int rg = row0 + trow * 8 + i;
    if (rg < nd) {
      *(float4*)(dst + (size_t)rg * DD + tcol * 8) =
          make_float4(acc[i][0], acc[i][1], acc[i][2], acc[i][3]);
      *(float4*)(dst + (size_t)rg * DD + tcol * 8 + 4) =
          make_float4(acc[i][4], acc[i][5], acc[i][6], acc[i][7]);
    }
  }
}

__global__ __launch_bounds__(256) void reduce_k(const float* __restrict__ part,
    float* __restrict__ hs, int n) {
  int i = blockIdx.x * 256 + threadIdx.x;
  if (i < n) {
    float4 s = make_float4(0.f, 0.f, 0.f, 0.f);
#pragma unroll
    for (int p = 0; p < KSPLIT; ++p) {
      float4 v = *(const float4*)(part + (size_t)p * n * 4 + i * 4);
      s.x += v.x; s.y += v.y; s.z += v.z; s.w += v.w;
    }
    *(float4*)(hs + (size_t)i * 4) = s;
  }
}

// ---------------- final blend into d_out at disease rows ----------------
__global__ __launch_bounds__(256) void final_k(const float* __restrict__ hs,
    const float* __restrict__ hbp, const float* __restrict__ rs,
    const int* __restrict__ bli, const int* __restrict__ deg,
    float* __restrict__ out, int nd) {
  int gid = blockIdx.x * 256 + threadIdx.x;
  int i = gid >> 5, q = gid & 31;
  if (i < nd) {
    int g = bli[i];
    float cg = 0.7f * expf(-0.7f * (float)deg[g]) + 0.2f;
    float inv = 1.0f / rs[i];
    float4 s = *(const float4*)(hs + (size_t)i * DD + q * 4);
    float4 b = *(const float4*)(hbp + (size_t)i * DD + q * 4);
    float4 o;
    o.x = cg * (s.x * inv) + (1.f - cg) * b.x;
    o.y = cg * (s.y * inv) + (1.f - cg) * b.y;
    o.z = cg * (s.z * inv) + (1.f - cg) * b.z;
    o.w = cg * (s.w * inv) + (1.f - cg) * b.w;
    *(float4*)(out + (size_t)g * DD + q * 4) = o;
  }
}

extern "C" void kernel_launch(void* const* d_in, const int* in_sizes, int n_in,
                              void* d_out, int out_size, void* d_ws, size_t ws_size,
                              hipStream_t stream) {
  const float* x   = (const float*)d_in[0];
  const float* sim = (const float*)d_in[1];
  const float* W1s = (const float*)d_in[2];
  const float* W1r = (const float*)d_in[3];
  const float* W2s = (const float*)d_in[4];
  const float* W2r = (const float*)d_in[5];
  const int* esrc  = (const int*)d_in[6];
  const int* edst  = (const int*)d_in[7];
  const int* etyp  = (const int*)d_in[8];
  const int* bli   = (const int*)d_in[9];
  const int* mri   = (const int*)d_in[10];
  const int N  = in_sizes[0] / DD;
  const int E  = in_sizes[6];
  const int ND = in_sizes[9];
  const int NR = N * RR;
  float* out = (float*)d_out;

  // workspace carve-up (~112 MB)
  char* w = (char*)d_ws;
  _Float16* msg = (_Float16*)w; w += (size_t)NR * DD * sizeof(_Float16);  // 82 MB
  _Float16* xh  = (_Float16*)w; w += (size_t)N * DD * sizeof(_Float16);
  _Float16* h1h = (_Float16*)w; w += (size_t)N * DD * sizeof(_Float16);
  _Float16* WT1 = (_Float16*)w; w += (size_t)DD * KK * sizeof(_Float16);
  _Float16* WT2 = (_Float16*)w; w += (size_t)DD * KK * sizeof(_Float16);
  float* hbp = (float*)w; w += (size_t)ND * DD * sizeof(float);
  float* hs  = (float*)w; w += (size_t)ND * DD * sizeof(float);
  int* cnt  = (int*)w; w += (size_t)NR * sizeof(int);
  int* deg  = (int*)w; w += (size_t)N * sizeof(int);
  int* off  = (int*)w; w += (size_t)NR * sizeof(int);
  int* cur  = (int*)w; w += (size_t)NR * sizeof(int);
  int* eidx = (int*)w; w += (size_t)E * sizeof(int);
  int* bsum = (int*)w; w += 1024 * sizeof(int);
  float* rs = (float*)w; w += (size_t)ND * sizeof(float);
  float* hs_part = (float*)msg;  // alias: msg dead once sim phase starts

  // ---- CSR build ----
  hipMemsetAsync(cnt, 0, (size_t)(NR + N) * sizeof(int), stream);
  count_k<<<(E + 255) / 256, 256, 0, stream>>>(edst, etyp, cnt, deg, E);
  int nblk = (NR + SCAN_CHUNK - 1) / SCAN_CHUNK;
  scan_a<<<nblk, 256, 0, stream>>>(cnt, off, bsum, NR);
  scan_b<<<1, 256, 0, stream>>>(bsum, nblk);
  scan_c<<<(NR + 255) / 256, 256, 0, stream>>>(off, bsum, NR);
  hipMemcpyAsync(cur, off, (size_t)NR * sizeof(int), hipMemcpyDeviceToDevice, stream);
  fill_k<<<(E + 255) / 256, 256, 0, stream>>>(esrc, edst, etyp, cur, eidx, E);

  // ---- f16 conversions ----
  convx_k<<<(N * DD / 4 + 255) / 256, 256, 0, stream>>>(x, xh, N * DD / 4);
  convw_k<<<(DD * KK + 255) / 256, 256, 0, stream>>>(W1s, W1r, WT1);
  convw_k<<<(DD * KK + 255) / 256, 256, 0, stream>>>(W2s, W2r, WT2);

  // ---- layer 1 ----
  agg_k<<<(NR * 32 + 255) / 256, 256, 0, stream>>>(xh, off, eidx, msg, NR, E);
  rgcn_mfma<true, true><<<(N + 127) / 128, 256, 0, stream>>>(xh, msg, WT1, h1h, N);

  // ---- layer 2 (writes all rows of d_out in fp32) ----
  agg_k<<<(NR * 32 + 255) / 256, 256, 0, stream>>>(h1h, off, eidx, msg, NR, E);
  rgcn_mfma<false, false><<<(N + 127) / 128, 256, 0, stream>>>(h1h, msg, WT2, out, N);

  // ---- similarity diffusion ----
  gather_k<<<(ND * 32 + 255) / 256, 256, 0, stream>>>(out, bli, hbp, ND);
  rowsum_k<<<ND, 256, 0, stream>>>(sim, mri, rs, ND);
  int chunk = (((ND + KSPLIT - 1) / KSPLIT) + 15) & ~15;
  dim3 sgrid((ND + 127) / 128, KSPLIT);
  sim_gemm_split<<<sgrid, 256, 0, stream>>>(sim, hbp, mri, hs_part, ND, chunk);
  reduce_k<<<(ND * DD / 4 + 255) / 256, 256, 0, stream>>>(hs_part, hs, ND * DD / 4);
  final_k<<<(ND * 32 + 255) / 256, 256, 0, stream>>>(hs, hbp, rs, bli, deg, out, ND);
}

// Round 4
// 347.722 us; speedup vs baseline: 10.4760x; 1.6186x over previous
//
#include <hip/hip_runtime.h>
#include <hip/hip_bf16.h>

#define DD 128
#define RR 8
#define KK 1152      // RGCN composite K = 128 + 8*128
#define SCAN_CHUNK 2048
#define KSPLIT 8
#define KP 4096      // padded sim K

typedef _Float16 h8 __attribute__((ext_vector_type(8)));
typedef _Float16 h4 __attribute__((ext_vector_type(4)));
typedef float f4 __attribute__((ext_vector_type(4)));

__device__ __forceinline__ void gload16(const _Float16* g, _Float16* l) {
  __builtin_amdgcn_global_load_lds(
      (const __attribute__((address_space(1))) void*)g,
      (__attribute__((address_space(3))) void*)l, 16, 0, 0);
}

// ---------------- count edges per (dst, rel) and in-degree ----------------
__global__ __launch_bounds__(256) void count_k(const int* __restrict__ edst,
    const int* __restrict__ etyp, int* __restrict__ cnt, int* __restrict__ deg, int E) {
  int i = blockIdx.x * 256 + threadIdx.x;
  if (i < E) {
    int d = edst[i];
    atomicAdd(&cnt[d * RR + etyp[i]], 1);
    atomicAdd(&deg[d], 1);
  }
}

// ---------------- 3-phase exclusive scan of cnt -> off ----------------
__global__ __launch_bounds__(256) void scan_a(const int* __restrict__ cnt,
    int* __restrict__ off, int* __restrict__ bsum, int n) {
  __shared__ int red[256];
  int base = blockIdx.x * SCAN_CHUNK + threadIdx.x * 8;
  int v[8];
  int s = 0;
#pragma unroll
  for (int i = 0; i < 8; ++i) {
    int idx = base + i;
    v[i] = s;
    s += (idx < n) ? cnt[idx] : 0;
  }
  red[threadIdx.x] = s;
  __syncthreads();
  for (int o = 1; o < 256; o <<= 1) {
    int t = (threadIdx.x >= o) ? red[threadIdx.x - o] : 0;
    __syncthreads();
    red[threadIdx.x] += t;
    __syncthreads();
  }
  int pre = (threadIdx.x > 0) ? red[threadIdx.x - 1] : 0;
#pragma unroll
  for (int i = 0; i < 8; ++i) {
    int idx = base + i;
    if (idx < n) off[idx] = v[i] + pre;
  }
  if (threadIdx.x == 255) bsum[blockIdx.x] = red[255];
}

__global__ void scan_b(int* __restrict__ bsum, int nb) {
  if (threadIdx.x == 0) {
    int s = 0;
    for (int i = 0; i < nb; ++i) { int t = bsum[i]; bsum[i] = s; s += t; }
  }
}

__global__ __launch_bounds__(256) void scan_c(int* __restrict__ off,
    const int* __restrict__ bsum, int n) {
  int i = blockIdx.x * 256 + threadIdx.x;
  if (i < n) off[i] += bsum[i >> 11];
}

// ---------------- fill CSR ----------------
__global__ __launch_bounds__(256) void fill_k(const int* __restrict__ esrc,
    const int* __restrict__ edst, const int* __restrict__ etyp,
    int* __restrict__ cur, int* __restrict__ eidx, int E) {
  int e = blockIdx.x * 256 + threadIdx.x;
  if (e < E) {
    int seg = edst[e] * RR + etyp[e];
    int p = atomicAdd(&cur[seg], 1);
    eidx[p] = esrc[e];
  }
}

// ---------------- fp32 -> f16 convert of x ----------------
__global__ __launch_bounds__(256) void convx_k(const float* __restrict__ x,
    _Float16* __restrict__ xh, int n4) {
  int i = blockIdx.x * 256 + threadIdx.x;
  if (i < n4) {
    float4 v = *(const float4*)(x + (size_t)i * 4);
    h4 o = {(_Float16)v.x, (_Float16)v.y, (_Float16)v.z, (_Float16)v.w};
    *(h4*)(xh + (size_t)i * 4) = o;
  }
}

// ---------------- build transposed f16 weights WT[n][k] ----------------
__global__ __launch_bounds__(256) void convw_k(const float* __restrict__ Ws,
    const float* __restrict__ Wr, _Float16* __restrict__ WT) {
  int gid = blockIdx.x * 256 + threadIdx.x;
  if (gid < DD * KK) {
    int n = gid / KK, k = gid % KK;
    float v = (k < DD) ? Ws[(size_t)k * DD + n] : Wr[(size_t)(k - DD) * DD + n];
    WT[gid] = (_Float16)v;
  }
}

// ---------------- gather-aggregate (f16 in/out, fp32 accumulate) ----------------
__global__ __launch_bounds__(256) void agg_k(const _Float16* __restrict__ h,
    const int* __restrict__ off, const int* __restrict__ eidx,
    _Float16* __restrict__ msg, int nseg, int E) {
  int gid = blockIdx.x * 256 + threadIdx.x;
  int seg = gid >> 5, q = gid & 31;
  if (seg >= nseg) return;
  int b = off[seg];
  int e = (seg + 1 < nseg) ? off[seg + 1] : E;
  float a0 = 0.f, a1 = 0.f, a2 = 0.f, a3 = 0.f;
  for (int i = b; i < e; ++i) {
    h4 v = *(const h4*)(h + (size_t)eidx[i] * DD + q * 4);
    a0 += (float)v[0]; a1 += (float)v[1]; a2 += (float)v[2]; a3 += (float)v[3];
  }
  float ic = (e > b) ? 1.0f / (float)(e - b) : 0.0f;
  h4 o = {(_Float16)(a0 * ic), (_Float16)(a1 * ic),
          (_Float16)(a2 * ic), (_Float16)(a3 * ic)};
  *(h4*)(msg + (size_t)seg * DD + q * 4) = o;
}

// ---------------- MFMA RGCN GEMM: out = [xh | msg] @ WT^T ----------------
// 64x128 tile, BK=64, 4 waves of 32x64, double-buffered LDS, global_load_lds
// staging (linear LDS dest, inverse-XOR-swizzled global source, XOR on read).
template <bool RELU, bool F16OUT>
__global__ __launch_bounds__(256) void rgcn_mfma(const _Float16* __restrict__ xh,
    const _Float16* __restrict__ msg, const _Float16* __restrict__ WT,
    void* __restrict__ outv, int nN) {
  __shared__ _Float16 Ab[2][64 * 64];
  __shared__ _Float16 Bb[2][128 * 64];
  const int t = threadIdx.x;
  const int lane = t & 63, w = t >> 6;
  const int row0 = blockIdx.x * 64;
  const int wm = w >> 1, wn = w & 1;
  const int lr = lane & 15, lg = lane >> 4;

  f4 acc[2][4];
#pragma unroll
  for (int mi = 0; mi < 2; ++mi)
#pragma unroll
    for (int ni = 0; ni < 4; ++ni) acc[mi][ni] = (f4){0.f, 0.f, 0.f, 0.f};

  // A staging: 512 chunks of 16B; lane handles q = j*256 + w*64 + lane
  const _Float16* pxh[2];
  const _Float16* pmsg[2];
  int ldsA[2];
#pragma unroll
  for (int j = 0; j < 2; ++j) {
    int q = j * 256 + w * 64 + lane;
    int row = q >> 3;
    int gck = (q & 7) ^ (row & 7);          // inverse swizzle on source
    int m = row0 + row; if (m >= nN) m = nN - 1;
    pxh[j]  = xh  + (size_t)m * DD + gck * 8;
    pmsg[j] = msg + (size_t)m * (RR * DD) + gck * 8;
    ldsA[j] = (j * 256 + w * 64) * 8;       // wave-uniform base (f16 units)
  }
  // B staging: 1024 chunks
  const _Float16* pB[4];
  int ldsB[4];
#pragma unroll
  for (int i = 0; i < 4; ++i) {
    int q = i * 256 + w * 64 + lane;
    int n = q >> 3;
    int gck = (q & 7) ^ (n & 7);
    pB[i] = WT + (size_t)n * KK + gck * 8;
    ldsB[i] = (i * 256 + w * 64) * 8;
  }

  const int nsteps = KK / 64;  // 18
  // prologue: stage tile 0 (k=0..63 < 128 -> xh)
#pragma unroll
  for (int j = 0; j < 2; ++j) gload16(pxh[j], &Ab[0][ldsA[j]]);
#pragma unroll
  for (int i = 0; i < 4; ++i) gload16(pB[i], &Bb[0][ldsB[i]]);
  asm volatile("s_waitcnt vmcnt(0)" ::: "memory");
  __syncthreads();

  for (int ts = 0; ts < nsteps; ++ts) {
    const int cur = ts & 1;
    if (ts + 1 < nsteps) {
      const int kk = (ts + 1) * 64;
      const int nxt = cur ^ 1;
      if (kk < DD) {
#pragma unroll
        for (int j = 0; j < 2; ++j) gload16(pxh[j] + kk, &Ab[nxt][ldsA[j]]);
      } else {
#pragma unroll
        for (int j = 0; j < 2; ++j) gload16(pmsg[j] + (kk - DD), &Ab[nxt][ldsA[j]]);
      }
#pragma unroll
      for (int i = 0; i < 4; ++i) gload16(pB[i] + kk, &Bb[nxt][ldsB[i]]);
    }
#pragma unroll
    for (int s = 0; s < 2; ++s) {
      h8 af[2], bf[4];
#pragma unroll
      for (int mi = 0; mi < 2; ++mi) {
        int r = wm * 32 + mi * 16 + lr;
        af[mi] = *(const h8*)&Ab[cur][r * 64 + (((s * 4 + lg) ^ (r & 7)) << 3)];
      }
#pragma unroll
      for (int ni = 0; ni < 4; ++ni) {
        int n = wn * 64 + ni * 16 + lr;
        bf[ni] = *(const h8*)&Bb[cur][n * 64 + (((s * 4 + lg) ^ (n & 7)) << 3)];
      }
#pragma unroll
      for (int mi = 0; mi < 2; ++mi)
#pragma unroll
        for (int ni = 0; ni < 4; ++ni)
          acc[mi][ni] = __builtin_amdgcn_mfma_f32_16x16x32_f16(
              af[mi], bf[ni], acc[mi][ni], 0, 0, 0);
    }
    asm volatile("s_waitcnt vmcnt(0)" ::: "memory");
    __syncthreads();
  }

  // epilogue: C/D layout col=lane&15, row=(lane>>4)*4+reg
#pragma unroll
  for (int mi = 0; mi < 2; ++mi) {
#pragma unroll
    for (int j = 0; j < 4; ++j) {
      int row = row0 + wm * 32 + mi * 16 + lg * 4 + j;
      if (row < nN) {
#pragma unroll
        for (int ni = 0; ni < 4; ++ni) {
          int col = wn * 64 + ni * 16 + lr;
          float v = acc[mi][ni][j];
          if (RELU) v = fmaxf(v, 0.f);
          if (F16OUT)
            ((_Float16*)outv)[(size_t)row * DD + col] = (_Float16)v;
          else
            ((float*)outv)[(size_t)row * DD + col] = v;
        }
      }
    }
  }
}

// ---------------- maskf scatter: maskf[mri[i]] = 1 ----------------
__global__ __launch_bounds__(256) void maskset_k(const int* __restrict__ mri,
    float* __restrict__ maskf, int nd) {
  int i = blockIdx.x * 256 + threadIdx.x;
  if (i < nd) maskf[mri[i]] = 1.0f;
}

// ---------------- sim row convert (gathered rows, contiguous cols) + fused rowsum ----------------
__global__ __launch_bounds__(256) void convsim_k(const float* __restrict__ sim,
    const int* __restrict__ mri, const float* __restrict__ maskf,
    _Float16* __restrict__ simh, float* __restrict__ rs, int nd) {
  __shared__ float red[256];
  int i = blockIdx.x;
  const float* row = sim + (size_t)mri[i] * nd;
  float acc = 0.f;
  for (int c4 = threadIdx.x; c4 < KP / 4; c4 += 256) {
    int c = c4 * 4;
    float4 v = make_float4(0.f, 0.f, 0.f, 0.f);
    if (c < nd) {
      v = *(const float4*)(row + c);
      float4 mk = *(const float4*)(maskf + c);
      acc += v.x * mk.x + v.y * mk.y + v.z * mk.z + v.w * mk.w;
    }
    h4 o = {(_Float16)v.x, (_Float16)v.y, (_Float16)v.z, (_Float16)v.w};
    *(h4*)(simh + (size_t)i * KP + c) = o;
  }
  red[threadIdx.x] = acc;
  __syncthreads();
  for (int o = 128; o > 0; o >>= 1) {
    if (threadIdx.x < o) red[threadIdx.x] += red[threadIdx.x + o];
    __syncthreads();
  }
  if (threadIdx.x == 0) rs[i] = red[0] + 1e-9f;
}

// ---------------- gather disease rows (fp32 hbp) + scatter f16 into hbs ----------------
__global__ __launch_bounds__(256) void gather2_k(const float* __restrict__ h2,
    const int* __restrict__ bli, const int* __restrict__ mri,
    float* __restrict__ hbp, _Float16* __restrict__ hbs, int nd) {
  int gid = blockIdx.x * 256 + threadIdx.x;
  int i = gid >> 5, q = gid & 31;
  if (i < nd) {
    float4 v = *(const float4*)(h2 + (size_t)bli[i] * DD + q * 4);
    *(float4*)(hbp + (size_t)i * DD + q * 4) = v;
    h4 o = {(_Float16)v.x, (_Float16)v.y, (_Float16)v.z, (_Float16)v.w};
    *(h4*)(hbs + (size_t)mri[i] * DD + q * 4) = o;
  }
}

// ---------------- transpose hbs[KP][128] -> hbsT[128][KP] ----------------
__global__ __launch_bounds__(256) void transpose_k(const _Float16* __restrict__ hbs,
    _Float16* __restrict__ hbsT) {
  __shared__ _Float16 tile[64][72];
  int r0 = blockIdx.x * 64, c0 = blockIdx.y * 64;
  int t = threadIdx.x;
  int r = t >> 2, cs = (t & 3) * 16;
  *(h8*)&tile[r][cs]     = *(const h8*)(hbs + (size_t)(r0 + r) * DD + c0 + cs);
  *(h8*)&tile[r][cs + 8] = *(const h8*)(hbs + (size_t)(r0 + r) * DD + c0 + cs + 8);
  __syncthreads();
  int n = t >> 2, rs2 = (t & 3) * 16;
  h8 o0, o1;
#pragma unroll
  for (int j = 0; j < 8; ++j) {
    o0[j] = tile[rs2 + j][n];
    o1[j] = tile[rs2 + 8 + j][n];
  }
  *(h8*)(hbsT + (size_t)(c0 + n) * KP + r0 + rs2)     = o0;
  *(h8*)(hbsT + (size_t)(c0 + n) * KP + r0 + rs2 + 8) = o1;
}

// ---------------- sim MFMA GEMM: hs_part[ky] = simh[:, kchunk] @ hbsT^T ----------------
__global__ __launch_bounds__(256) void sim_mfma(const _Float16* __restrict__ simh,
    const _Float16* __restrict__ hbsT, float* __restrict__ hs_part, int nd) {
  __shared__ _Float16 Ab[2][64 * 64];
  __shared__ _Float16 Bb[2][128 * 64];
  const int t = threadIdx.x;
  const int lane = t & 63, w = t >> 6;
  const int row0 = blockIdx.x * 64;
  const int kb0 = blockIdx.y * (KP / KSPLIT);   // 512
  const int wm = w >> 1, wn = w & 1;
  const int lr = lane & 15, lg = lane >> 4;

  f4 acc[2][4];
#pragma unroll
  for (int mi = 0; mi < 2; ++mi)
#pragma unroll
    for (int ni = 0; ni < 4; ++ni) acc[mi][ni] = (f4){0.f, 0.f, 0.f, 0.f};

  const _Float16* pA[2];
  int ldsA[2];
#pragma unroll
  for (int j = 0; j < 2; ++j) {
    int q = j * 256 + w * 64 + lane;
    int row = q >> 3;
    int gck = (q & 7) ^ (row & 7);
    int m = row0 + row; if (m >= nd) m = nd - 1;
    pA[j] = simh + (size_t)m * KP + kb0 + gck * 8;
    ldsA[j] = (j * 256 + w * 64) * 8;
  }
  const _Float16* pB[4];
  int ldsB[4];
#pragma unroll
  for (int i = 0; i < 4; ++i) {
    int q = i * 256 + w * 64 + lane;
    int n = q >> 3;
    int gck = (q & 7) ^ (n & 7);
    pB[i] = hbsT + (size_t)n * KP + kb0 + gck * 8;
    ldsB[i] = (i * 256 + w * 64) * 8;
  }

  const int nsteps = (KP / KSPLIT) / 64;  // 8
#pragma unroll
  for (int j = 0; j < 2; ++j) gload16(pA[j], &Ab[0][ldsA[j]]);
#pragma unroll
  for (int i = 0; i < 4; ++i) gload16(pB[i], &Bb[0][ldsB[i]]);
  asm volatile("s_waitcnt vmcnt(0)" ::: "memory");
  __syncthreads();

  for (int ts = 0; ts < nsteps; ++ts) {
    const int cur = ts & 1;
    if (ts + 1 < nsteps) {
      const int kk = (ts + 1) * 64;
      const int nxt = cur ^ 1;
#pragma unroll
      for (int j = 0; j < 2; ++j) gload16(pA[j] + kk, &Ab[nxt][ldsA[j]]);
#pragma unroll
      for (int i = 0; i < 4; ++i) gload16(pB[i] + kk, &Bb[nxt][ldsB[i]]);
    }
#pragma unroll
    for (int s = 0; s < 2; ++s) {
      h8 af[2], bf[4];
#pragma unroll
      for (int mi = 0; mi < 2; ++mi) {
        int r = wm * 32 + mi * 16 + lr;
        af[mi] = *(const h8*)&Ab[cur][r * 64 + (((s * 4 + lg) ^ (r & 7)) << 3)];
      }
#pragma unroll
      for (int ni = 0; ni < 4; ++ni) {
        int n = wn * 64 + ni * 16 + lr;
        bf[ni] = *(const h8*)&Bb[cur][n * 64 + (((s * 4 + lg) ^ (n & 7)) << 3)];
      }
#pragma unroll
      for (int mi = 0; mi < 2; ++mi)
#pragma unroll
        for (int ni = 0; ni < 4; ++ni)
          acc[mi][ni] = __builtin_amdgcn_mfma_f32_16x16x32_f16(
              af[mi], bf[ni], acc[mi][ni], 0, 0, 0);
    }
    asm volatile("s_waitcnt vmcnt(0)" ::: "memory");
    __syncthreads();
  }

  float* dst = hs_part + (size_t)blockIdx.y * nd * DD;
#pragma unroll
  for (int mi = 0; mi < 2; ++mi) {
#pragma unroll
    for (int j = 0; j < 4; ++j) {
      int row = row0 + wm * 32 + mi * 16 + lg * 4 + j;
      if (row < nd) {
#pragma unroll
        for (int ni = 0; ni < 4; ++ni) {
          int col = wn * 64 + ni * 16 + lr;
          dst[(size_t)row * DD + col] = acc[mi][ni][j];
        }
      }
    }
  }
}

__global__ __launch_bounds__(256) void reduce_k(const float* __restrict__ part,
    float* __restrict__ hs, int n) {  // n = nd*DD/4 float4s
  int i = blockIdx.x * 256 + threadIdx.x;
  if (i < n) {
    float4 s = make_float4(0.f, 0.f, 0.f, 0.f);
#pragma unroll
    for (int p = 0; p < KSPLIT; ++p) {
      float4 v = *(const float4*)(part + (size_t)p * n * 4 + i * 4);
      s.x += v.x; s.y += v.y; s.z += v.z; s.w += v.w;
    }
    *(float4*)(hs + (size_t)i * 4) = s;
  }
}

// ---------------- final blend into d_out at disease rows ----------------
__global__ __launch_bounds__(256) void final_k(const float* __restrict__ hs,
    const float* __restrict__ hbp, const float* __restrict__ rs,
    const int* __restrict__ bli, const int* __restrict__ deg,
    float* __restrict__ out, int nd) {
  int gid = blockIdx.x * 256 + threadIdx.x;
  int i = gid >> 5, q = gid & 31;
  if (i < nd) {
    int g = bli[i];
    float cg = 0.7f * expf(-0.7f * (float)deg[g]) + 0.2f;
    float inv = 1.0f / rs[i];
    float4 s = *(const float4*)(hs + (size_t)i * DD + q * 4);
    float4 b = *(const float4*)(hbp + (size_t)i * DD + q * 4);
    float4 o;
    o.x = cg * (s.x * inv) + (1.f - cg) * b.x;
    o.y = cg * (s.y * inv) + (1.f - cg) * b.y;
    o.z = cg * (s.z * inv) + (1.f - cg) * b.z;
    o.w = cg * (s.w * inv) + (1.f - cg) * b.w;
    *(float4*)(out + (size_t)g * DD + q * 4) = o;
  }
}

extern "C" void kernel_launch(void* const* d_in, const int* in_sizes, int n_in,
                              void* d_out, int out_size, void* d_ws, size_t ws_size,
                              hipStream_t stream) {
  const float* x   = (const float*)d_in[0];
  const float* sim = (const float*)d_in[1];
  const float* W1s = (const float*)d_in[2];
  const float* W1r = (const float*)d_in[3];
  const float* W2s = (const float*)d_in[4];
  const float* W2r = (const float*)d_in[5];
  const int* esrc  = (const int*)d_in[6];
  const int* edst  = (const int*)d_in[7];
  const int* etyp  = (const int*)d_in[8];
  const int* bli   = (const int*)d_in[9];
  const int* mri   = (const int*)d_in[10];
  const int N  = in_sizes[0] / DD;
  const int E  = in_sizes[6];
  const int ND = in_sizes[9];
  const int NR = N * RR;
  float* out = (float*)d_out;

  // workspace carve-up (~148 MB)
  char* w = (char*)d_ws;
  _Float16* msg  = (_Float16*)w; w += (size_t)NR * DD * sizeof(_Float16);   // 82 MB
  _Float16* xh   = (_Float16*)w; w += (size_t)N * DD * sizeof(_Float16);
  _Float16* h1h  = (_Float16*)w; w += (size_t)N * DD * sizeof(_Float16);
  _Float16* WT1  = (_Float16*)w; w += (size_t)DD * KK * sizeof(_Float16);
  _Float16* WT2  = (_Float16*)w; w += (size_t)DD * KK * sizeof(_Float16);
  _Float16* simh = (_Float16*)w; w += (size_t)ND * KP * sizeof(_Float16);   // 32.8 MB
  _Float16* hbs  = (_Float16*)w; w += (size_t)KP * DD * sizeof(_Float16);   // 1 MB
  _Float16* hbsT = (_Float16*)w; w += (size_t)DD * KP * sizeof(_Float16);   // 1 MB
  float* hbp   = (float*)w; w += (size_t)ND * DD * sizeof(float);
  float* hs    = (float*)w; w += (size_t)ND * DD * sizeof(float);
  float* maskf = (float*)w; w += (size_t)KP * sizeof(float);
  int* cnt  = (int*)w; w += (size_t)NR * sizeof(int);
  int* deg  = (int*)w; w += (size_t)N * sizeof(int);
  int* off  = (int*)w; w += (size_t)NR * sizeof(int);
  int* cur  = (int*)w; w += (size_t)NR * sizeof(int);
  int* eidx = (int*)w; w += (size_t)E * sizeof(int);
  int* bsum = (int*)w; w += 1024 * sizeof(int);
  float* rs = (float*)w; w += (size_t)ND * sizeof(float);
  float* hs_part = (float*)msg;  // alias: msg dead once sim GEMM runs (16.4 MB < 82 MB)

  // ---- CSR build ----
  hipMemsetAsync(cnt, 0, (size_t)(NR + N) * sizeof(int), stream);
  count_k<<<(E + 255) / 256, 256, 0, stream>>>(edst, etyp, cnt, deg, E);
  int nblk = (NR + SCAN_CHUNK - 1) / SCAN_CHUNK;
  scan_a<<<nblk, 256, 0, stream>>>(cnt, off, bsum, NR);
  scan_b<<<1, 256, 0, stream>>>(bsum, nblk);
  scan_c<<<(NR + 255) / 256, 256, 0, stream>>>(off, bsum, NR);
  hipMemcpyAsync(cur, off, (size_t)NR * sizeof(int), hipMemcpyDeviceToDevice, stream);
  fill_k<<<(E + 255) / 256, 256, 0, stream>>>(esrc, edst, etyp, cur, eidx, E);

  // ---- f16 conversions ----
  convx_k<<<(N * DD / 4 + 255) / 256, 256, 0, stream>>>(x, xh, N * DD / 4);
  convw_k<<<(DD * KK + 255) / 256, 256, 0, stream>>>(W1s, W1r, WT1);
  convw_k<<<(DD * KK + 255) / 256, 256, 0, stream>>>(W2s, W2r, WT2);

  // ---- sim preprocessing (independent of RGCN) ----
  hipMemsetAsync(maskf, 0, (size_t)KP * sizeof(float), stream);
  maskset_k<<<(ND + 255) / 256, 256, 0, stream>>>(mri, maskf, ND);
  convsim_k<<<ND, 256, 0, stream>>>(sim, mri, maskf, simh, rs, ND);

  // ---- layer 1 ----
  agg_k<<<(NR * 32 + 255) / 256, 256, 0, stream>>>(xh, off, eidx, msg, NR, E);
  rgcn_mfma<true, true><<<(N + 63) / 64, 256, 0, stream>>>(xh, msg, WT1, h1h, N);

  // ---- layer 2 (writes all rows of d_out in fp32) ----
  agg_k<<<(NR * 32 + 255) / 256, 256, 0, stream>>>(h1h, off, eidx, msg, NR, E);
  rgcn_mfma<false, false><<<(N + 63) / 64, 256, 0, stream>>>(h1h, msg, WT2, out, N);

  // ---- similarity diffusion ----
  hipMemsetAsync(hbs, 0, (size_t)KP * DD * sizeof(_Float16), stream);
  gather2_k<<<(ND * 32 + 255) / 256, 256, 0, stream>>>(out, bli, mri, hbp, hbs, ND);
  dim3 tgrid(KP / 64, DD / 64);
  transpose_k<<<tgrid, 256, 0, stream>>>(hbs, hbsT);
  dim3 sgrid((ND + 63) / 64, KSPLIT);
  sim_mfma<<<sgrid, 256, 0, stream>>>(simh, hbsT, hs_part, ND);
  reduce_k<<<(ND * DD / 4 + 255) / 256, 256, 0, stream>>>(hs_part, hs, ND * DD / 4);
  final_k<<<(ND * 32 + 255) / 256, 256, 0, stream>>>(hs, hbp, rs, bli, deg, out, ND);
}

// Round 5
// 343.539 us; speedup vs baseline: 10.6035x; 1.0122x over previous
//
#include <hip/hip_runtime.h>
#include <hip/hip_bf16.h>

#define DD 128
#define RR 8
#define KK 1152      // RGCN composite K = 128 + 8*128
#define SCAN_CHUNK 2048
#define KSPLIT 8
#define KP 4096      // padded sim K

typedef _Float16 h8 __attribute__((ext_vector_type(8)));
typedef _Float16 h4 __attribute__((ext_vector_type(4)));
typedef float f4 __attribute__((ext_vector_type(4)));

__device__ __forceinline__ void gload16(const _Float16* g, _Float16* l) {
  __builtin_amdgcn_global_load_lds(
      (const __attribute__((address_space(1))) void*)g,
      (__attribute__((address_space(3))) void*)l, 16, 0, 0);
}

// ---------------- count edges per (dst, rel) and in-degree ----------------
__global__ __launch_bounds__(256) void count_k(const int* __restrict__ edst,
    const int* __restrict__ etyp, int* __restrict__ cnt, int* __restrict__ deg, int E) {
  int i = blockIdx.x * 256 + threadIdx.x;
  if (i < E) {
    int d = edst[i];
    atomicAdd(&cnt[d * RR + etyp[i]], 1);
    atomicAdd(&deg[d], 1);
  }
}

// ---------------- 3-phase exclusive scan of cnt -> off ----------------
__global__ __launch_bounds__(256) void scan_a(const int* __restrict__ cnt,
    int* __restrict__ off, int* __restrict__ bsum, int n) {
  __shared__ int red[256];
  int base = blockIdx.x * SCAN_CHUNK + threadIdx.x * 8;
  int v[8];
  int s = 0;
#pragma unroll
  for (int i = 0; i < 8; ++i) {
    int idx = base + i;
    v[i] = s;
    s += (idx < n) ? cnt[idx] : 0;
  }
  red[threadIdx.x] = s;
  __syncthreads();
  for (int o = 1; o < 256; o <<= 1) {
    int t = (threadIdx.x >= o) ? red[threadIdx.x - o] : 0;
    __syncthreads();
    red[threadIdx.x] += t;
    __syncthreads();
  }
  int pre = (threadIdx.x > 0) ? red[threadIdx.x - 1] : 0;
#pragma unroll
  for (int i = 0; i < 8; ++i) {
    int idx = base + i;
    if (idx < n) off[idx] = v[i] + pre;
  }
  if (threadIdx.x == 255) bsum[blockIdx.x] = red[255];
}

__global__ void scan_b(int* __restrict__ bsum, int nb) {
  if (threadIdx.x == 0) {
    int s = 0;
    for (int i = 0; i < nb; ++i) { int t = bsum[i]; bsum[i] = s; s += t; }
  }
}

__global__ __launch_bounds__(256) void scan_c(int* __restrict__ off,
    const int* __restrict__ bsum, int n) {
  int i = blockIdx.x * 256 + threadIdx.x;
  if (i < n) off[i] += bsum[i >> 11];
}

// ---------------- fill CSR ----------------
__global__ __launch_bounds__(256) void fill_k(const int* __restrict__ esrc,
    const int* __restrict__ edst, const int* __restrict__ etyp,
    int* __restrict__ cur, int* __restrict__ eidx, int E) {
  int e = blockIdx.x * 256 + threadIdx.x;
  if (e < E) {
    int seg = edst[e] * RR + etyp[e];
    int p = atomicAdd(&cur[seg], 1);
    eidx[p] = esrc[e];
  }
}

// ---------------- fp32 -> f16 convert of x ----------------
__global__ __launch_bounds__(256) void convx_k(const float* __restrict__ x,
    _Float16* __restrict__ xh, int n4) {
  int i = blockIdx.x * 256 + threadIdx.x;
  if (i < n4) {
    float4 v = *(const float4*)(x + (size_t)i * 4);
    h4 o = {(_Float16)v.x, (_Float16)v.y, (_Float16)v.z, (_Float16)v.w};
    *(h4*)(xh + (size_t)i * 4) = o;
  }
}

// ---------------- build transposed f16 weights WT[n][k] ----------------
__global__ __launch_bounds__(256) void convw_k(const float* __restrict__ Ws,
    const float* __restrict__ Wr, _Float16* __restrict__ WT) {
  int gid = blockIdx.x * 256 + threadIdx.x;
  if (gid < DD * KK) {
    int n = gid / KK, k = gid % KK;
    float v = (k < DD) ? Ws[(size_t)k * DD + n] : Wr[(size_t)(k - DD) * DD + n];
    WT[gid] = (_Float16)v;
  }
}

// ---------------- FUSED RGCN layer: out = [h | per-(dst,r)-mean(h[src])] @ WT^T ----
// 64x128 tile, BK=64, 18 K-steps. Steps 0-1: A = h rows via global_load_lds.
// Steps 2-17: A tile computed on the fly from the CSR (gather + mean + ds_write).
template <bool RELU, bool F16OUT>
__global__ __launch_bounds__(256) void rgcn_fused(const _Float16* __restrict__ hfeat,
    const int* __restrict__ off, const int* __restrict__ eidx,
    const _Float16* __restrict__ WT, void* __restrict__ outv, int nN, int E) {
  __shared__ _Float16 Ab[2][64 * 64];
  __shared__ _Float16 Bb[2][128 * 64];
  const int t = threadIdx.x;
  const int lane = t & 63, w = t >> 6;
  const int row0 = blockIdx.x * 64;
  const int wm = w >> 1, wn = w & 1;
  const int lr = lane & 15, lg = lane >> 4;
  const int NRtot = nN * RR;

  f4 acc[2][4];
#pragma unroll
  for (int mi = 0; mi < 2; ++mi)
#pragma unroll
    for (int ni = 0; ni < 4; ++ni) acc[mi][ni] = (f4){0.f, 0.f, 0.f, 0.f};

  // A gload staging (steps 0,1 only): 512 16B chunks, linear LDS dest,
  // inverse-XOR-swizzled global source.
  const _Float16* pxh[2];
  int ldsA[2];
#pragma unroll
  for (int j = 0; j < 2; ++j) {
    int q = j * 256 + w * 64 + lane;
    int row = q >> 3;
    int gck = (q & 7) ^ (row & 7);
    int m = row0 + row; if (m >= nN) m = nN - 1;
    pxh[j] = hfeat + (size_t)m * DD + gck * 8;
    ldsA[j] = (j * 256 + w * 64) * 8;
  }
  // B staging: 1024 chunks
  const _Float16* pB[4];
  int ldsB[4];
#pragma unroll
  for (int i = 0; i < 4; ++i) {
    int q = i * 256 + w * 64 + lane;
    int n = q >> 3;
    int gck = (q & 7) ^ (n & 7);
    pB[i] = WT + (size_t)n * KK + gck * 8;
    ldsB[i] = (i * 256 + w * 64) * 8;
  }

  // gather role: 4 threads per row, 16 k-cols (2 chunks) each
  const int grow = t >> 2, gsub = t & 3;
  const int gm = row0 + grow;
  const int segbase = gm * RR;

  const int nsteps = KK / 64;  // 18
  // prologue: stage tile 0
#pragma unroll
  for (int j = 0; j < 2; ++j) gload16(pxh[j], &Ab[0][ldsA[j]]);
#pragma unroll
  for (int i = 0; i < 4; ++i) gload16(pB[i], &Bb[0][ldsB[i]]);
  asm volatile("s_waitcnt vmcnt(0)" ::: "memory");
  __syncthreads();

  for (int ts = 0; ts < nsteps; ++ts) {
    const int cur = ts & 1;
    const int nxt = cur ^ 1;
    if (ts + 1 < nsteps) {
      const int tsn = ts + 1;
      const int kk = tsn * 64;
#pragma unroll
      for (int i = 0; i < 4; ++i) gload16(pB[i] + kk, &Bb[nxt][ldsB[i]]);
      if (tsn < 2) {
#pragma unroll
        for (int j = 0; j < 2; ++j) gload16(pxh[j] + kk, &Ab[nxt][ldsA[j]]);
      } else {
        // on-the-fly aggregation for relation r, column half hh
        const int r = (tsn - 2) >> 1;
        const int hh = (tsn - 2) & 1;
        const int seg = segbase + r;
        const int b = off[seg];
        const int e = (seg + 1 < NRtot) ? off[seg + 1] : E;
        float a[16];
#pragma unroll
        for (int i = 0; i < 16; ++i) a[i] = 0.f;
        for (int i = b; i < e; ++i) {
          const _Float16* hp = hfeat + (size_t)eidx[i] * DD + hh * 64 + gsub * 16;
          h8 v0 = *(const h8*)hp;
          h8 v1 = *(const h8*)(hp + 8);
#pragma unroll
          for (int j = 0; j < 8; ++j) {
            a[j] += (float)v0[j];
            a[8 + j] += (float)v1[j];
          }
        }
        float ic = (e > b) ? 1.0f / (float)(e - b) : 0.0f;
        h8 o0, o1;
#pragma unroll
        for (int j = 0; j < 8; ++j) {
          o0[j] = (_Float16)(a[j] * ic);
          o1[j] = (_Float16)(a[8 + j] * ic);
        }
        const int c0 = gsub * 2;
        *(h8*)&Ab[nxt][grow * 64 + ((c0 ^ (grow & 7)) << 3)] = o0;
        *(h8*)&Ab[nxt][grow * 64 + (((c0 + 1) ^ (grow & 7)) << 3)] = o1;
      }
    }
#pragma unroll
    for (int s = 0; s < 2; ++s) {
      h8 af[2], bf[4];
#pragma unroll
      for (int mi = 0; mi < 2; ++mi) {
        int rr = wm * 32 + mi * 16 + lr;
        af[mi] = *(const h8*)&Ab[cur][rr * 64 + (((s * 4 + lg) ^ (rr & 7)) << 3)];
      }
#pragma unroll
      for (int ni = 0; ni < 4; ++ni) {
        int n = wn * 64 + ni * 16 + lr;
        bf[ni] = *(const h8*)&Bb[cur][n * 64 + (((s * 4 + lg) ^ (n & 7)) << 3)];
      }
#pragma unroll
      for (int mi = 0; mi < 2; ++mi)
#pragma unroll
        for (int ni = 0; ni < 4; ++ni)
          acc[mi][ni] = __builtin_amdgcn_mfma_f32_16x16x32_f16(
              af[mi], bf[ni], acc[mi][ni], 0, 0, 0);
    }
    asm volatile("s_waitcnt vmcnt(0)" ::: "memory");
    __syncthreads();
  }

  // epilogue: C/D layout col=lane&15, row=(lane>>4)*4+reg
#pragma unroll
  for (int mi = 0; mi < 2; ++mi) {
#pragma unroll
    for (int j = 0; j < 4; ++j) {
      int row = row0 + wm * 32 + mi * 16 + lg * 4 + j;
      if (row < nN) {
#pragma unroll
        for (int ni = 0; ni < 4; ++ni) {
          int col = wn * 64 + ni * 16 + lr;
          float v = acc[mi][ni][j];
          if (RELU) v = fmaxf(v, 0.f);
          if (F16OUT)
            ((_Float16*)outv)[(size_t)row * DD + col] = (_Float16)v;
          else
            ((float*)outv)[(size_t)row * DD + col] = v;
        }
      }
    }
  }
}

// ---------------- maskf scatter: maskf[mri[i]] = 1 ----------------
__global__ __launch_bounds__(256) void maskset_k(const int* __restrict__ mri,
    float* __restrict__ maskf, int nd) {
  int i = blockIdx.x * 256 + threadIdx.x;
  if (i < nd) maskf[mri[i]] = 1.0f;
}

// ---------------- sim row convert + fused rowsum ----------------
__global__ __launch_bounds__(256) void convsim_k(const float* __restrict__ sim,
    const int* __restrict__ mri, const float* __restrict__ maskf,
    _Float16* __restrict__ simh, float* __restrict__ rs, int nd) {
  __shared__ float red[256];
  int i = blockIdx.x;
  const float* row = sim + (size_t)mri[i] * nd;
  float acc = 0.f;
  for (int c4 = threadIdx.x; c4 < KP / 4; c4 += 256) {
    int c = c4 * 4;
    float4 v = make_float4(0.f, 0.f, 0.f, 0.f);
    if (c < nd) {
      v = *(const float4*)(row + c);
      float4 mk = *(const float4*)(maskf + c);
      acc += v.x * mk.x + v.y * mk.y + v.z * mk.z + v.w * mk.w;
    }
    h4 o = {(_Float16)v.x, (_Float16)v.y, (_Float16)v.z, (_Float16)v.w};
    *(h4*)(simh + (size_t)i * KP + c) = o;
  }
  red[threadIdx.x] = acc;
  __syncthreads();
  for (int o = 128; o > 0; o >>= 1) {
    if (threadIdx.x < o) red[threadIdx.x] += red[threadIdx.x + o];
    __syncthreads();
  }
  if (threadIdx.x == 0) rs[i] = red[0] + 1e-9f;
}

// ---------------- gather disease rows (fp32 hbp) + scatter f16 into hbs ----------------
__global__ __launch_bounds__(256) void gather2_k(const float* __restrict__ h2,
    const int* __restrict__ bli, const int* __restrict__ mri,
    float* __restrict__ hbp, _Float16* __restrict__ hbs, int nd) {
  int gid = blockIdx.x * 256 + threadIdx.x;
  int i = gid >> 5, q = gid & 31;
  if (i < nd) {
    float4 v = *(const float4*)(h2 + (size_t)bli[i] * DD + q * 4);
    *(float4*)(hbp + (size_t)i * DD + q * 4) = v;
    h4 o = {(_Float16)v.x, (_Float16)v.y, (_Float16)v.z, (_Float16)v.w};
    *(h4*)(hbs + (size_t)mri[i] * DD + q * 4) = o;
  }
}

// ---------------- transpose hbs[KP][128] -> hbsT[128][KP] ----------------
__global__ __launch_bounds__(256) void transpose_k(const _Float16* __restrict__ hbs,
    _Float16* __restrict__ hbsT) {
  __shared__ _Float16 tile[64][72];
  int r0 = blockIdx.x * 64, c0 = blockIdx.y * 64;
  int t = threadIdx.x;
  int r = t >> 2, cs = (t & 3) * 16;
  *(h8*)&tile[r][cs]     = *(const h8*)(hbs + (size_t)(r0 + r) * DD + c0 + cs);
  *(h8*)&tile[r][cs + 8] = *(const h8*)(hbs + (size_t)(r0 + r) * DD + c0 + cs + 8);
  __syncthreads();
  int n = t >> 2, rs2 = (t & 3) * 16;
  h8 o0, o1;
#pragma unroll
  for (int j = 0; j < 8; ++j) {
    o0[j] = tile[rs2 + j][n];
    o1[j] = tile[rs2 + 8 + j][n];
  }
  *(h8*)(hbsT + (size_t)(c0 + n) * KP + r0 + rs2)     = o0;
  *(h8*)(hbsT + (size_t)(c0 + n) * KP + r0 + rs2 + 8) = o1;
}

// ---------------- sim MFMA GEMM: hs_part[ky] = simh[:, kchunk] @ hbsT^T ----------------
__global__ __launch_bounds__(256) void sim_mfma(const _Float16* __restrict__ simh,
    const _Float16* __restrict__ hbsT, float* __restrict__ hs_part, int nd) {
  __shared__ _Float16 Ab[2][64 * 64];
  __shared__ _Float16 Bb[2][128 * 64];
  const int t = threadIdx.x;
  const int lane = t & 63, w = t >> 6;
  const int row0 = blockIdx.x * 64;
  const int kb0 = blockIdx.y * (KP / KSPLIT);   // 512
  const int wm = w >> 1, wn = w & 1;
  const int lr = lane & 15, lg = lane >> 4;

  f4 acc[2][4];
#pragma unroll
  for (int mi = 0; mi < 2; ++mi)
#pragma unroll
    for (int ni = 0; ni < 4; ++ni) acc[mi][ni] = (f4){0.f, 0.f, 0.f, 0.f};

  const _Float16* pA[2];
  int ldsA[2];
#pragma unroll
  for (int j = 0; j < 2; ++j) {
    int q = j * 256 + w * 64 + lane;
    int row = q >> 3;
    int gck = (q & 7) ^ (row & 7);
    int m = row0 + row; if (m >= nd) m = nd - 1;
    pA[j] = simh + (size_t)m * KP + kb0 + gck * 8;
    ldsA[j] = (j * 256 + w * 64) * 8;
  }
  const _Float16* pB[4];
  int ldsB[4];
#pragma unroll
  for (int i = 0; i < 4; ++i) {
    int q = i * 256 + w * 64 + lane;
    int n = q >> 3;
    int gck = (q & 7) ^ (n & 7);
    pB[i] = hbsT + (size_t)n * KP + kb0 + gck * 8;
    ldsB[i] = (i * 256 + w * 64) * 8;
  }

  const int nsteps = (KP / KSPLIT) / 64;  // 8
#pragma unroll
  for (int j = 0; j < 2; ++j) gload16(pA[j], &Ab[0][ldsA[j]]);
#pragma unroll
  for (int i = 0; i < 4; ++i) gload16(pB[i], &Bb[0][ldsB[i]]);
  asm volatile("s_waitcnt vmcnt(0)" ::: "memory");
  __syncthreads();

  for (int ts = 0; ts < nsteps; ++ts) {
    const int cur = ts & 1;
    if (ts + 1 < nsteps) {
      const int kk = (ts + 1) * 64;
      const int nxt = cur ^ 1;
#pragma unroll
      for (int j = 0; j < 2; ++j) gload16(pA[j] + kk, &Ab[nxt][ldsA[j]]);
#pragma unroll
      for (int i = 0; i < 4; ++i) gload16(pB[i] + kk, &Bb[nxt][ldsB[i]]);
    }
#pragma unroll
    for (int s = 0; s < 2; ++s) {
      h8 af[2], bf[4];
#pragma unroll
      for (int mi = 0; mi < 2; ++mi) {
        int r = wm * 32 + mi * 16 + lr;
        af[mi] = *(const h8*)&Ab[cur][r * 64 + (((s * 4 + lg) ^ (r & 7)) << 3)];
      }
#pragma unroll
      for (int ni = 0; ni < 4; ++ni) {
        int n = wn * 64 + ni * 16 + lr;
        bf[ni] = *(const h8*)&Bb[cur][n * 64 + (((s * 4 + lg) ^ (n & 7)) << 3)];
      }
#pragma unroll
      for (int mi = 0; mi < 2; ++mi)
#pragma unroll
        for (int ni = 0; ni < 4; ++ni)
          acc[mi][ni] = __builtin_amdgcn_mfma_f32_16x16x32_f16(
              af[mi], bf[ni], acc[mi][ni], 0, 0, 0);
    }
    asm volatile("s_waitcnt vmcnt(0)" ::: "memory");
    __syncthreads();
  }

  float* dst = hs_part + (size_t)blockIdx.y * nd * DD;
#pragma unroll
  for (int mi = 0; mi < 2; ++mi) {
#pragma unroll
    for (int j = 0; j < 4; ++j) {
      int row = row0 + wm * 32 + mi * 16 + lg * 4 + j;
      if (row < nd) {
#pragma unroll
        for (int ni = 0; ni < 4; ++ni) {
          int col = wn * 64 + ni * 16 + lr;
          dst[(size_t)row * DD + col] = acc[mi][ni][j];
        }
      }
    }
  }
}

__global__ __launch_bounds__(256) void reduce_k(const float* __restrict__ part,
    float* __restrict__ hs, int n) {
  int i = blockIdx.x * 256 + threadIdx.x;
  if (i < n) {
    float4 s = make_float4(0.f, 0.f, 0.f, 0.f);
#pragma unroll
    for (int p = 0; p < KSPLIT; ++p) {
      float4 v = *(const float4*)(part + (size_t)p * n * 4 + i * 4);
      s.x += v.x; s.y += v.y; s.z += v.z; s.w += v.w;
    }
    *(float4*)(hs + (size_t)i * 4) = s;
  }
}

// ---------------- final blend into d_out at disease rows ----------------
__global__ __launch_bounds__(256) void final_k(const float* __restrict__ hs,
    const float* __restrict__ hbp, const float* __restrict__ rs,
    const int* __restrict__ bli, const int* __restrict__ deg,
    float* __restrict__ out, int nd) {
  int gid = blockIdx.x * 256 + threadIdx.x;
  int i = gid >> 5, q = gid & 31;
  if (i < nd) {
    int g = bli[i];
    float cg = 0.7f * expf(-0.7f * (float)deg[g]) + 0.2f;
    float inv = 1.0f / rs[i];
    float4 s = *(const float4*)(hs + (size_t)i * DD + q * 4);
    float4 b = *(const float4*)(hbp + (size_t)i * DD + q * 4);
    float4 o;
    o.x = cg * (s.x * inv) + (1.f - cg) * b.x;
    o.y = cg * (s.y * inv) + (1.f - cg) * b.y;
    o.z = cg * (s.z * inv) + (1.f - cg) * b.z;
    o.w = cg * (s.w * inv) + (1.f - cg) * b.w;
    *(float4*)(out + (size_t)g * DD + q * 4) = o;
  }
}

extern "C" void kernel_launch(void* const* d_in, const int* in_sizes, int n_in,
                              void* d_out, int out_size, void* d_ws, size_t ws_size,
                              hipStream_t stream) {
  const float* x   = (const float*)d_in[0];
  const float* sim = (const float*)d_in[1];
  const float* W1s = (const float*)d_in[2];
  const float* W1r = (const float*)d_in[3];
  const float* W2s = (const float*)d_in[4];
  const float* W2r = (const float*)d_in[5];
  const int* esrc  = (const int*)d_in[6];
  const int* edst  = (const int*)d_in[7];
  const int* etyp  = (const int*)d_in[8];
  const int* bli   = (const int*)d_in[9];
  const int* mri   = (const int*)d_in[10];
  const int N  = in_sizes[0] / DD;
  const int E  = in_sizes[6];
  const int ND = in_sizes[9];
  const int NR = N * RR;
  float* out = (float*)d_out;

  // workspace carve-up (~83 MB)
  char* w = (char*)d_ws;
  _Float16* xh   = (_Float16*)w; w += (size_t)N * DD * sizeof(_Float16);
  _Float16* h1h  = (_Float16*)w; w += (size_t)N * DD * sizeof(_Float16);
  _Float16* WT1  = (_Float16*)w; w += (size_t)DD * KK * sizeof(_Float16);
  _Float16* WT2  = (_Float16*)w; w += (size_t)DD * KK * sizeof(_Float16);
  _Float16* simh = (_Float16*)w; w += (size_t)ND * KP * sizeof(_Float16);
  _Float16* hbs  = (_Float16*)w; w += (size_t)KP * DD * sizeof(_Float16);
  _Float16* hbsT = (_Float16*)w; w += (size_t)DD * KP * sizeof(_Float16);
  float* hs_part = (float*)w; w += (size_t)KSPLIT * ND * DD * sizeof(float);
  float* hbp   = (float*)w; w += (size_t)ND * DD * sizeof(float);
  float* hs    = (float*)w; w += (size_t)ND * DD * sizeof(float);
  float* maskf = (float*)w; w += (size_t)KP * sizeof(float);
  int* cnt  = (int*)w; w += (size_t)NR * sizeof(int);
  int* deg  = (int*)w; w += (size_t)N * sizeof(int);
  int* off  = (int*)w; w += (size_t)NR * sizeof(int);
  int* cur  = (int*)w; w += (size_t)NR * sizeof(int);
  int* eidx = (int*)w; w += (size_t)E * sizeof(int);
  int* bsum = (int*)w; w += 1024 * sizeof(int);
  float* rs = (float*)w; w += (size_t)ND * sizeof(float);

  // ---- CSR build ----
  hipMemsetAsync(cnt, 0, (size_t)(NR + N) * sizeof(int), stream);
  count_k<<<(E + 255) / 256, 256, 0, stream>>>(edst, etyp, cnt, deg, E);
  int nblk = (NR + SCAN_CHUNK - 1) / SCAN_CHUNK;
  scan_a<<<nblk, 256, 0, stream>>>(cnt, off, bsum, NR);
  scan_b<<<1, 256, 0, stream>>>(bsum, nblk);
  scan_c<<<(NR + 255) / 256, 256, 0, stream>>>(off, bsum, NR);
  hipMemcpyAsync(cur, off, (size_t)NR * sizeof(int), hipMemcpyDeviceToDevice, stream);
  fill_k<<<(E + 255) / 256, 256, 0, stream>>>(esrc, edst, etyp, cur, eidx, E);

  // ---- f16 conversions ----
  convx_k<<<(N * DD / 4 + 255) / 256, 256, 0, stream>>>(x, xh, N * DD / 4);
  convw_k<<<(DD * KK + 255) / 256, 256, 0, stream>>>(W1s, W1r, WT1);
  convw_k<<<(DD * KK + 255) / 256, 256, 0, stream>>>(W2s, W2r, WT2);

  // ---- sim preprocessing (independent of RGCN) ----
  hipMemsetAsync(maskf, 0, (size_t)KP * sizeof(float), stream);
  maskset_k<<<(ND + 255) / 256, 256, 0, stream>>>(mri, maskf, ND);
  convsim_k<<<ND, 256, 0, stream>>>(sim, mri, maskf, simh, rs, ND);

  // ---- fused RGCN layers ----
  rgcn_fused<true, true><<<(N + 63) / 64, 256, 0, stream>>>(
      xh, off, eidx, WT1, h1h, N, E);
  rgcn_fused<false, false><<<(N + 63) / 64, 256, 0, stream>>>(
      h1h, off, eidx, WT2, out, N, E);

  // ---- similarity diffusion ----
  hipMemsetAsync(hbs, 0, (size_t)KP * DD * sizeof(_Float16), stream);
  gather2_k<<<(ND * 32 + 255) / 256, 256, 0, stream>>>(out, bli, mri, hbp, hbs, ND);
  dim3 tgrid(KP / 64, DD / 64);
  transpose_k<<<tgrid, 256, 0, stream>>>(hbs, hbsT);
  dim3 sgrid((ND + 63) / 64, KSPLIT);
  sim_mfma<<<sgrid, 256, 0, stream>>>(simh, hbsT, hs_part, ND);
  reduce_k<<<(ND * DD / 4 + 255) / 256, 256, 0, stream>>>(hs_part, hs, ND * DD / 4);
  final_k<<<(ND * 32 + 255) / 256, 256, 0, stream>>>(hs, hbp, rs, bli, deg, out, ND);
}